// Round 1
// baseline (243.770 us; speedup 1.0000x reference)
//
#include <hip/hip_runtime.h>
#include <math.h>

#define Q_TOTAL 21760
#define D_MODEL 256
#define N_HEADS 8
#define HEAD_DIM 32
#define N_LEVELS 4
#define N_POINTS 4

// ---------------------------------------------------------------------------
// Generic f32 GEMM: C[row][ldc] (cols colBase..colBase+63) = A[M][256] @ W[N][256]^T + bias
// BM=64, BN=64, BK=16, 256 threads, 4x4 per-thread microtile.
// M and N are exact multiples of 64 in all our launches (M=21760=340*64).
// ---------------------------------------------------------------------------
__global__ __launch_bounds__(256) void gemm_tn(
    const float* __restrict__ A,
    const float* __restrict__ W,
    const float* __restrict__ bias,
    float* __restrict__ C,
    int ldc)
{
    constexpr int K = 256, BM = 64, BK = 16;
    __shared__ float As[BK][BM];   // As[k][m]
    __shared__ float Bs[BK][BM];   // Bs[k][n]

    const int tid = threadIdx.x;
    const int tx = tid & 15;       // 16 col groups
    const int ty = tid >> 4;       // 16 row groups
    const int rowBase = blockIdx.x * BM;
    const int colBase = blockIdx.y * BM;

    const int ldRow = tid >> 2;          // 0..63
    const int ldK0  = (tid & 3) << 2;    // 0,4,8,12

    const float* Ap = A + (size_t)(rowBase + ldRow) * K + ldK0;
    const float* Wp = W + (size_t)(colBase + ldRow) * K + ldK0;

    float acc[4][4] = {};

    for (int kt = 0; kt < K; kt += BK) {
        float4 av = *(const float4*)(Ap + kt);
        float4 wv = *(const float4*)(Wp + kt);
        __syncthreads();
        As[ldK0 + 0][ldRow] = av.x; As[ldK0 + 1][ldRow] = av.y;
        As[ldK0 + 2][ldRow] = av.z; As[ldK0 + 3][ldRow] = av.w;
        Bs[ldK0 + 0][ldRow] = wv.x; Bs[ldK0 + 1][ldRow] = wv.y;
        Bs[ldK0 + 2][ldRow] = wv.z; Bs[ldK0 + 3][ldRow] = wv.w;
        __syncthreads();
#pragma unroll
        for (int kk = 0; kk < BK; kk++) {
            float4 a4 = *(const float4*)&As[kk][ty * 4];
            float4 b4 = *(const float4*)&Bs[kk][tx * 4];
            float ar[4] = {a4.x, a4.y, a4.z, a4.w};
            float br[4] = {b4.x, b4.y, b4.z, b4.w};
#pragma unroll
            for (int i = 0; i < 4; i++)
#pragma unroll
                for (int j = 0; j < 4; j++)
                    acc[i][j] += ar[i] * br[j];
        }
    }

    float bv[4];
#pragma unroll
    for (int j = 0; j < 4; j++) bv[j] = bias[colBase + tx * 4 + j];
#pragma unroll
    for (int i = 0; i < 4; i++) {
        float4 o = make_float4(acc[i][0] + bv[0], acc[i][1] + bv[1],
                               acc[i][2] + bv[2], acc[i][3] + bv[3]);
        *(float4*)&C[(size_t)(rowBase + ty * 4 + i) * ldc + colBase + tx * 4] = o;
    }
}

// ---------------------------------------------------------------------------
// Sampling kernel: one block (256 threads) per query.
// offattn: [Q][384] = 256 offsets + 128 attn logits per query.
// value:   [Q][256] (pixel-major, col = head*32 + dim)
// ---------------------------------------------------------------------------
__global__ __launch_bounds__(256) void sample_kernel(
    const float* __restrict__ value,
    const float* __restrict__ offattn,
    const float* __restrict__ refpts,   // [Q][4][2]
    float* __restrict__ sampled)        // [Q][256]
{
    const int q = blockIdx.x;
    const int tid = threadIdx.x;

    __shared__ float s_logit[128];
    __shared__ float s_aw[128];
    __shared__ int   s_idx[128 * 4];
    __shared__ float s_w[128 * 4];

    const float* oa = offattn + (size_t)q * 384;

    if (tid < 128) s_logit[tid] = oa[256 + tid];
    __syncthreads();

    if (tid < N_HEADS) {
        float m = -1e30f;
#pragma unroll
        for (int i = 0; i < 16; i++) m = fmaxf(m, s_logit[tid * 16 + i]);
        float e[16];
        float sum = 0.f;
#pragma unroll
        for (int i = 0; i < 16; i++) { e[i] = __expf(s_logit[tid * 16 + i] - m); sum += e[i]; }
        float inv = 1.f / sum;
#pragma unroll
        for (int i = 0; i < 16; i++) s_aw[tid * 16 + i] = e[i] * inv;
    }
    __syncthreads();

    if (tid < 128) {
        // tid = h*16 + l*4 + p
        const int l = (tid >> 2) & 3;
        const int sz[4]    = {128, 64, 32, 16};
        const int start[4] = {0, 16384, 20480, 21504};
        const float s = (float)sz[l];
        const float ox = oa[tid * 2 + 0];
        const float oy = oa[tid * 2 + 1];
        const float rx = refpts[(size_t)q * 8 + l * 2 + 0];
        const float ry = refpts[(size_t)q * 8 + l * 2 + 1];
        // loc = ref + off/ (w,h);  gx = loc*w - 0.5
        const float gx = (rx + ox / s) * s - 0.5f;
        const float gy = (ry + oy / s) * s - 0.5f;
        const float x0f = floorf(gx), y0f = floorf(gy);
        const float lx = gx - x0f, ly = gy - y0f;
        const int x0 = (int)x0f, y0 = (int)y0f;
        const float aw = s_aw[tid];
        const int W_ = sz[l];
#pragma unroll
        for (int tap = 0; tap < 4; tap++) {
            const int dx = tap & 1, dy = tap >> 1;
            const int xi = x0 + dx, yi = y0 + dy;
            const bool valid = (xi >= 0) & (xi < W_) & (yi >= 0) & (yi < W_);
            const float wx = dx ? lx : (1.f - lx);
            const float wy = dy ? ly : (1.f - ly);
            s_idx[tid * 4 + tap] = valid ? (start[l] + yi * W_ + xi) : 0;
            s_w[tid * 4 + tap]   = valid ? (wx * wy * aw) : 0.f;
        }
    }
    __syncthreads();

    // tid = h*32 + d ; accumulate 16 points * 4 taps
    const int h = tid >> 5;
    const float* vbase = value + tid;   // value[pix*256 + h*32 + d]
    float acc = 0.f;
#pragma unroll 4
    for (int lp = 0; lp < 16; lp++) {
        const int o = (h * 16 + lp) * 4;
#pragma unroll
        for (int tap = 0; tap < 4; tap++) {
            const int   idx = s_idx[o + tap];
            const float w   = s_w[o + tap];
            acc += w * vbase[(size_t)idx * 256];
        }
    }
    sampled[(size_t)q * 256 + tid] = acc;
}

// ---------------------------------------------------------------------------
extern "C" void kernel_launch(void* const* d_in, const int* in_sizes, int n_in,
                              void* d_out, int out_size, void* d_ws, size_t ws_size,
                              hipStream_t stream) {
    const float* query  = (const float*)d_in[0];
    const float* refpts = (const float*)d_in[1];
    const float* input_flatten = (const float*)d_in[2];
    // d_in[3] spatial shapes, d_in[4] level starts: hard-coded constants
    const float* W_off  = (const float*)d_in[5];
    const float* b_off  = (const float*)d_in[6];
    const float* W_attn = (const float*)d_in[7];
    const float* b_attn = (const float*)d_in[8];
    const float* W_val  = (const float*)d_in[9];
    const float* b_val  = (const float*)d_in[10];
    const float* W_out  = (const float*)d_in[11];
    const float* b_out  = (const float*)d_in[12];
    float* out = (float*)d_out;

    char* ws = (char*)d_ws;
    float* value   = (float*)(ws);                                  // Q*256 f32
    float* offattn = (float*)(ws + (size_t)Q_TOTAL * 256 * 4);      // Q*384 f32
    float* sampled = (float*)(ws + (size_t)Q_TOTAL * (256 + 384) * 4); // Q*256 f32

    dim3 blk(256);
    // value = input_flatten @ W_val^T + b_val
    gemm_tn<<<dim3(340, 4), blk, 0, stream>>>(input_flatten, W_val, b_val, value, 256);
    // offsets = query @ W_off^T + b_off  (cols 0..255 of offattn)
    gemm_tn<<<dim3(340, 4), blk, 0, stream>>>(query, W_off, b_off, offattn, 384);
    // attn logits = query @ W_attn^T + b_attn  (cols 256..383 of offattn)
    gemm_tn<<<dim3(340, 2), blk, 0, stream>>>(query, W_attn, b_attn, offattn + 256, 384);
    // bilinear sampling + attention-weighted sum
    sample_kernel<<<dim3(Q_TOTAL), blk, 0, stream>>>(value, offattn, refpts, sampled);
    // out = sampled @ W_out^T + b_out
    gemm_tn<<<dim3(340, 4), blk, 0, stream>>>(sampled, W_out, b_out, out, 256);
}

// Round 2
// 132.309 us; speedup vs baseline: 1.8424x; 1.8424x over previous
//
#include <hip/hip_runtime.h>
#include <math.h>

#define Q_TOTAL 21760
#define NBLK_M 340   // 21760 / 64

typedef short  s16x8 __attribute__((ext_vector_type(8)));
typedef __bf16 bfv8  __attribute__((ext_vector_type(8)));
typedef float  f32x4 __attribute__((ext_vector_type(4)));

__device__ __forceinline__ float bf2f(unsigned short h) {
    union { unsigned int u; float f; } c; c.u = ((unsigned int)h) << 16; return c.f;
}

// pack 8 floats -> 8 bf16 (RNE via hardware cvt; compiler fuses to v_cvt_pk_bf16_f32)
__device__ __forceinline__ s16x8 pack8(float4 a, float4 b) {
    bfv8 t;
    t[0] = (__bf16)a.x; t[1] = (__bf16)a.y; t[2] = (__bf16)a.z; t[3] = (__bf16)a.w;
    t[4] = (__bf16)b.x; t[5] = (__bf16)b.y; t[6] = (__bf16)b.z; t[7] = (__bf16)b.w;
    return __builtin_bit_cast(s16x8, t);
}

// ---------------------------------------------------------------------------
// Convert the 4 weight matrices to bf16 in one pass.
// dst layout: [W_off 65536 | W_attn 32768 | W_val 65536 | W_out 65536]
// ---------------------------------------------------------------------------
__global__ __launch_bounds__(256) void cvt_weights(
    const float* __restrict__ Woff, const float* __restrict__ Wattn,
    const float* __restrict__ Wval, const float* __restrict__ Wout,
    unsigned short* __restrict__ dst)
{
    const int e = blockIdx.x * 1024 + threadIdx.x * 4;
    const float* src; int base;
    if (e < 65536)       { src = Woff;  base = 0; }
    else if (e < 98304)  { src = Wattn; base = 65536; }
    else if (e < 163840) { src = Wval;  base = 98304; }
    else                 { src = Wout;  base = 163840; }
    float4 v = *(const float4*)(src + (e - base));
    ushort4 o;
    o.x = __builtin_bit_cast(unsigned short, (__bf16)v.x);
    o.y = __builtin_bit_cast(unsigned short, (__bf16)v.y);
    o.z = __builtin_bit_cast(unsigned short, (__bf16)v.z);
    o.w = __builtin_bit_cast(unsigned short, (__bf16)v.w);
    *(ushort4*)(dst + e) = o;
}

// ---------------------------------------------------------------------------
// MFMA bf16 GEMM: C[M][ldc] = A[M][256] @ W[N][256]^T + bias
// BM=64, BN=N (256 or 128), BK=32, 256 threads = 4 waves (2x2).
// Wave (wr,wc): rows wr*32..+31, cols wc*BN/2..+BN/2-1; 2 x NF frags of 16x16.
// LDS tiles XOR-swizzled (byte ^= (row&7)<<4) -> ds_read_b128 2-way (free).
// ---------------------------------------------------------------------------
template<int BN, bool A_BF16, bool C_BF16>
__global__ __launch_bounds__(256) void gemm_mfma(
    const void* __restrict__ Avoid,
    const unsigned short* __restrict__ W16,
    const float* __restrict__ bias,
    void* __restrict__ Cvoid,
    int ldc)
{
    constexpr int K = 256, BM = 64;
    constexpr int NB2 = BN / 2;
    constexpr int NF = NB2 / 16;
    __shared__ unsigned short As[BM * 32];
    __shared__ unsigned short Bs[BN * 32];

    const int tid  = threadIdx.x;
    const int lane = tid & 63;
    const int wv   = tid >> 6;
    const int wr   = wv >> 1, wc = wv & 1;
    const int rowBase = blockIdx.x * BM;

    const int sr    = tid >> 2;          // staging row 0..63
    const int skq   = (tid & 3) * 8;     // 8 elems per thread along K
    const int sslot = (tid & 3) * 16;    // byte slot within 64B row

    f32x4 acc[2][NF];
#pragma unroll
    for (int i = 0; i < 2; i++)
#pragma unroll
        for (int j = 0; j < NF; j++) acc[i][j] = (f32x4){0.f, 0.f, 0.f, 0.f};

    const size_t arow = (size_t)(rowBase + sr) * K;

    for (int kt = 0; kt < K; kt += 32) {
        // ---- global loads (regs) ----
        s16x8 aval;
        if constexpr (A_BF16) {
            const unsigned short* A16 = (const unsigned short*)Avoid;
            aval = *(const s16x8*)(A16 + arow + kt + skq);
        } else {
            const float* A32 = (const float*)Avoid;
            const float* p = A32 + arow + kt + skq;
            aval = pack8(*(const float4*)p, *(const float4*)(p + 4));
        }
        s16x8 bval[BN / 64];
#pragma unroll
        for (int c = 0; c < BN / 64; c++) {
            const unsigned short* p = W16 + (size_t)(c * 64 + sr) * K + kt + skq;
            bval[c] = *(const s16x8*)p;
        }
        // ---- stage to LDS (swizzled) ----
        __syncthreads();
        *(s16x8*)(As + (((sr * 64 + sslot) ^ ((sr & 7) << 4)) >> 1)) = aval;
#pragma unroll
        for (int c = 0; c < BN / 64; c++) {
            const int row = c * 64 + sr;
            *(s16x8*)(Bs + (((row * 64 + sslot) ^ ((row & 7) << 4)) >> 1)) = bval[c];
        }
        __syncthreads();
        // ---- fragments + MFMA ----
        s16x8 af[2];
#pragma unroll
        for (int mi = 0; mi < 2; mi++) {
            const int row = wr * 32 + mi * 16 + (lane & 15);
            af[mi] = *(const s16x8*)(As + (((row * 64 + (lane >> 4) * 16) ^ ((row & 7) << 4)) >> 1));
        }
#pragma unroll
        for (int ni = 0; ni < NF; ni++) {
            const int row = wc * NB2 + ni * 16 + (lane & 15);
            s16x8 bfrag = *(const s16x8*)(Bs + (((row * 64 + (lane >> 4) * 16) ^ ((row & 7) << 4)) >> 1));
#pragma unroll
            for (int mi = 0; mi < 2; mi++)
                acc[mi][ni] = __builtin_amdgcn_mfma_f32_16x16x32_bf16(af[mi], bfrag, acc[mi][ni], 0, 0, 0);
        }
    }

    // ---- epilogue: C/D layout col=lane&15, row=(lane>>4)*4+j ----
#pragma unroll
    for (int ni = 0; ni < NF; ni++) {
        const int col = wc * NB2 + ni * 16 + (lane & 15);
        const float bv = bias[col];
#pragma unroll
        for (int mi = 0; mi < 2; mi++) {
            const int r0 = rowBase + wr * 32 + mi * 16 + (lane >> 4) * 4;
#pragma unroll
            for (int j = 0; j < 4; j++) {
                const float v = acc[mi][ni][j] + bv;
                if constexpr (C_BF16) {
                    ((unsigned short*)Cvoid)[(size_t)(r0 + j) * ldc + col] =
                        __builtin_bit_cast(unsigned short, (__bf16)v);
                } else {
                    ((float*)Cvoid)[(size_t)(r0 + j) * ldc + col] = v;
                }
            }
        }
    }
}

// ---------------------------------------------------------------------------
// Sampling kernel: one block (256 threads) per query. value/sampled are bf16.
// ---------------------------------------------------------------------------
__global__ __launch_bounds__(256) void sample_kernel(
    const unsigned short* __restrict__ value,   // [Q][256] bf16
    const float* __restrict__ offattn,          // [Q][384]
    const float* __restrict__ refpts,           // [Q][4][2]
    unsigned short* __restrict__ sampled)       // [Q][256] bf16
{
    const int q = blockIdx.x;
    const int tid = threadIdx.x;

    __shared__ float s_logit[128];
    __shared__ float s_aw[128];
    __shared__ int   s_idx[128 * 4];
    __shared__ float s_w[128 * 4];

    const float* oa = offattn + (size_t)q * 384;

    if (tid < 128) s_logit[tid] = oa[256 + tid];
    __syncthreads();

    if (tid < 8) {
        float m = -1e30f;
#pragma unroll
        for (int i = 0; i < 16; i++) m = fmaxf(m, s_logit[tid * 16 + i]);
        float e[16]; float sum = 0.f;
#pragma unroll
        for (int i = 0; i < 16; i++) { e[i] = __expf(s_logit[tid * 16 + i] - m); sum += e[i]; }
        const float inv = 1.f / sum;
#pragma unroll
        for (int i = 0; i < 16; i++) s_aw[tid * 16 + i] = e[i] * inv;
    }
    __syncthreads();

    if (tid < 128) {
        // tid = h*16 + l*4 + p
        const int l = (tid >> 2) & 3;
        const int sz[4]    = {128, 64, 32, 16};
        const int start[4] = {0, 16384, 20480, 21504};
        const float s = (float)sz[l];
        const float ox = oa[tid * 2 + 0];
        const float oy = oa[tid * 2 + 1];
        const float rx = refpts[(size_t)q * 8 + l * 2 + 0];
        const float ry = refpts[(size_t)q * 8 + l * 2 + 1];
        const float gx = (rx + ox / s) * s - 0.5f;
        const float gy = (ry + oy / s) * s - 0.5f;
        const float x0f = floorf(gx), y0f = floorf(gy);
        const float lx = gx - x0f, ly = gy - y0f;
        const int x0 = (int)x0f, y0 = (int)y0f;
        const float aw = s_aw[tid];
        const int W_ = sz[l];
#pragma unroll
        for (int tap = 0; tap < 4; tap++) {
            const int dx = tap & 1, dy = tap >> 1;
            const int xi = x0 + dx, yi = y0 + dy;
            const bool valid = (xi >= 0) & (xi < W_) & (yi >= 0) & (yi < W_);
            const float wx = dx ? lx : (1.f - lx);
            const float wy = dy ? ly : (1.f - ly);
            s_idx[tid * 4 + tap] = valid ? (start[l] + yi * W_ + xi) : 0;
            s_w[tid * 4 + tap]   = valid ? (wx * wy * aw) : 0.f;
        }
    }
    __syncthreads();

    // tid = h*32 + d ; accumulate 16 points * 4 taps
    const int h = tid >> 5;
    const unsigned short* vbase = value + tid;
    float acc = 0.f;
#pragma unroll 4
    for (int lp = 0; lp < 16; lp++) {
        const int o = (h * 16 + lp) * 4;
#pragma unroll
        for (int tap = 0; tap < 4; tap++) {
            const int   idx = s_idx[o + tap];
            const float w   = s_w[o + tap];
            acc += w * bf2f(vbase[(size_t)idx * 256]);
        }
    }
    sampled[(size_t)q * 256 + tid] = __builtin_bit_cast(unsigned short, (__bf16)acc);
}

// ---------------------------------------------------------------------------
extern "C" void kernel_launch(void* const* d_in, const int* in_sizes, int n_in,
                              void* d_out, int out_size, void* d_ws, size_t ws_size,
                              hipStream_t stream) {
    const float* query  = (const float*)d_in[0];
    const float* refpts = (const float*)d_in[1];
    const float* input_flatten = (const float*)d_in[2];
    const float* W_off  = (const float*)d_in[5];
    const float* b_off  = (const float*)d_in[6];
    const float* W_attn = (const float*)d_in[7];
    const float* b_attn = (const float*)d_in[8];
    const float* W_val  = (const float*)d_in[9];
    const float* b_val  = (const float*)d_in[10];
    const float* W_out  = (const float*)d_in[11];
    const float* b_out  = (const float*)d_in[12];
    float* out = (float*)d_out;

    char* ws = (char*)d_ws;
    unsigned short* value   = (unsigned short*)ws;                        // Q*256 bf16
    float*          offattn = (float*)(ws + 11141120);                    // Q*384 f32
    unsigned short* sampled = (unsigned short*)(ws + 11141120 + 33423360);// Q*256 bf16
    unsigned short* w16     = (unsigned short*)(ws + 11141120 + 33423360 + 11141120);
    unsigned short* w16_off  = w16;
    unsigned short* w16_attn = w16 + 65536;
    unsigned short* w16_val  = w16 + 98304;
    unsigned short* w16_out  = w16 + 163840;

    cvt_weights<<<224, 256, 0, stream>>>(W_off, W_attn, W_val, W_out, w16);

    // value = input_flatten @ W_val^T + b_val  (bf16 out)
    gemm_mfma<256, false, true ><<<NBLK_M, 256, 0, stream>>>(input_flatten, w16_val, b_val, value, 256);
    // offsets = query @ W_off^T + b_off  (cols 0..255 of offattn)
    gemm_mfma<256, false, false><<<NBLK_M, 256, 0, stream>>>(query, w16_off, b_off, offattn, 384);
    // attn logits = query @ W_attn^T + b_attn  (cols 256..383 of offattn)
    gemm_mfma<128, false, false><<<NBLK_M, 256, 0, stream>>>(query, w16_attn, b_attn, offattn + 256, 384);
    // bilinear sampling + attention-weighted sum (bf16 in/out)
    sample_kernel<<<Q_TOTAL, 256, 0, stream>>>(value, offattn, refpts, sampled);
    // out = sampled @ W_out^T + b_out
    gemm_mfma<256, true,  false><<<NBLK_M, 256, 0, stream>>>(sampled, w16_out, b_out, out, 256);
}

// Round 3
// 98.774 us; speedup vs baseline: 2.4679x; 1.3395x over previous
//
#include <hip/hip_runtime.h>
#include <math.h>

#define Q_TOTAL 21760
#define NBLK_M 340   // 21760 / 64
#define QB 8         // queries per sampling block

typedef short        s16x8 __attribute__((ext_vector_type(8)));
typedef __bf16       bfv8  __attribute__((ext_vector_type(8)));
typedef float        f32x4 __attribute__((ext_vector_type(4)));
typedef unsigned int u32x4 __attribute__((ext_vector_type(4)));

// pack 8 floats -> 8 bf16 (RNE; compiler emits v_cvt_pk_bf16_f32)
__device__ __forceinline__ s16x8 pack8(float4 a, float4 b) {
    bfv8 t;
    t[0] = (__bf16)a.x; t[1] = (__bf16)a.y; t[2] = (__bf16)a.z; t[3] = (__bf16)a.w;
    t[4] = (__bf16)b.x; t[5] = (__bf16)b.y; t[6] = (__bf16)b.z; t[7] = (__bf16)b.w;
    return __builtin_bit_cast(s16x8, t);
}

// ---------------------------------------------------------------------------
// Convert the 4 weight matrices to bf16 + build concat bias [b_off|b_attn].
// dst layout: [W_off 65536 | W_attn 32768 | W_val 65536 | W_out 65536]
// ---------------------------------------------------------------------------
__global__ __launch_bounds__(256) void cvt_weights(
    const float* __restrict__ Woff, const float* __restrict__ Wattn,
    const float* __restrict__ Wval, const float* __restrict__ Wout,
    const float* __restrict__ boff, const float* __restrict__ battn,
    unsigned short* __restrict__ dst, float* __restrict__ bias_cat)
{
    if (blockIdx.x == 224) {
        const int t = threadIdx.x;
        bias_cat[t] = boff[t];
        if (t < 128) bias_cat[256 + t] = battn[t];
        return;
    }
    const int e = blockIdx.x * 1024 + threadIdx.x * 4;
    const float* src; int base;
    if (e < 65536)       { src = Woff;  base = 0; }
    else if (e < 98304)  { src = Wattn; base = 65536; }
    else if (e < 163840) { src = Wval;  base = 98304; }
    else                 { src = Wout;  base = 163840; }
    float4 v = *(const float4*)(src + (e - base));
    ushort4 o;
    o.x = __builtin_bit_cast(unsigned short, (__bf16)v.x);
    o.y = __builtin_bit_cast(unsigned short, (__bf16)v.y);
    o.z = __builtin_bit_cast(unsigned short, (__bf16)v.z);
    o.w = __builtin_bit_cast(unsigned short, (__bf16)v.w);
    *(ushort4*)(dst + e) = o;
}

// ---------------------------------------------------------------------------
// MFMA bf16 GEMM: C[M][ldc] = A[M][256] @ W[N][256]^T + bias
// BM=64, BN in {256,384}, BK=32, 256 threads = 4 waves (2x2).
// LDS tiles XOR-swizzled (byte ^= (row&7)<<4) -> ds_read_b128 2-way (free).
// ---------------------------------------------------------------------------
template<int BN, bool A_BF16, bool C_BF16>
__global__ __launch_bounds__(256) void gemm_mfma(
    const void* __restrict__ Avoid,
    const unsigned short* __restrict__ W16,
    const float* __restrict__ bias,
    void* __restrict__ Cvoid,
    int ldc)
{
    constexpr int K = 256, BM = 64;
    constexpr int NB2 = BN / 2;
    constexpr int NF = NB2 / 16;
    __shared__ unsigned short As[BM * 32];
    __shared__ unsigned short Bs[BN * 32];

    const int tid  = threadIdx.x;
    const int lane = tid & 63;
    const int wv   = tid >> 6;
    const int wr   = wv >> 1, wc = wv & 1;
    const int rowBase = blockIdx.x * BM;

    const int sr    = tid >> 2;          // staging row 0..63
    const int skq   = (tid & 3) * 8;     // 8 elems per thread along K
    const int sslot = (tid & 3) * 16;    // byte slot within 64B row

    f32x4 acc[2][NF];
#pragma unroll
    for (int i = 0; i < 2; i++)
#pragma unroll
        for (int j = 0; j < NF; j++) acc[i][j] = (f32x4){0.f, 0.f, 0.f, 0.f};

    const size_t arow = (size_t)(rowBase + sr) * K;

    for (int kt = 0; kt < K; kt += 32) {
        s16x8 aval;
        if constexpr (A_BF16) {
            const unsigned short* A16 = (const unsigned short*)Avoid;
            aval = *(const s16x8*)(A16 + arow + kt + skq);
        } else {
            const float* A32 = (const float*)Avoid;
            const float* p = A32 + arow + kt + skq;
            aval = pack8(*(const float4*)p, *(const float4*)(p + 4));
        }
        s16x8 bval[BN / 64];
#pragma unroll
        for (int c = 0; c < BN / 64; c++) {
            const unsigned short* p = W16 + (size_t)(c * 64 + sr) * K + kt + skq;
            bval[c] = *(const s16x8*)p;
        }
        __syncthreads();
        *(s16x8*)(As + (((sr * 64 + sslot) ^ ((sr & 7) << 4)) >> 1)) = aval;
#pragma unroll
        for (int c = 0; c < BN / 64; c++) {
            const int row = c * 64 + sr;
            *(s16x8*)(Bs + (((row * 64 + sslot) ^ ((row & 7) << 4)) >> 1)) = bval[c];
        }
        __syncthreads();
        s16x8 af[2];
#pragma unroll
        for (int mi = 0; mi < 2; mi++) {
            const int row = wr * 32 + mi * 16 + (lane & 15);
            af[mi] = *(const s16x8*)(As + (((row * 64 + (lane >> 4) * 16) ^ ((row & 7) << 4)) >> 1));
        }
#pragma unroll
        for (int ni = 0; ni < NF; ni++) {
            const int row = wc * NB2 + ni * 16 + (lane & 15);
            s16x8 bfrag = *(const s16x8*)(Bs + (((row * 64 + (lane >> 4) * 16) ^ ((row & 7) << 4)) >> 1));
#pragma unroll
            for (int mi = 0; mi < 2; mi++)
                acc[mi][ni] = __builtin_amdgcn_mfma_f32_16x16x32_bf16(af[mi], bfrag, acc[mi][ni], 0, 0, 0);
        }
    }

#pragma unroll
    for (int ni = 0; ni < NF; ni++) {
        const int col = wc * NB2 + ni * 16 + (lane & 15);
        const float bv = bias[col];
#pragma unroll
        for (int mi = 0; mi < 2; mi++) {
            const int r0 = rowBase + wr * 32 + mi * 16 + (lane >> 4) * 4;
#pragma unroll
            for (int j = 0; j < 4; j++) {
                const float v = acc[mi][ni][j] + bv;
                if constexpr (C_BF16) {
                    ((unsigned short*)Cvoid)[(size_t)(r0 + j) * ldc + col] =
                        __builtin_bit_cast(unsigned short, (__bf16)v);
                } else {
                    ((float*)Cvoid)[(size_t)(r0 + j) * ldc + col] = v;
                }
            }
        }
    }
}

// ---------------------------------------------------------------------------
// Sampling: block = 8 queries x 32 threads. Phase 1 computes softmax +
// (idx, weight) per tap into LDS; phase 2 gathers 16B/tap per thread.
// Thread map P2: tid = ql*32 + h*4 + d8 (d8 = 8-dim group).
// s_iw groups padded to stride 65 -> the 16 concurrent (q,h) groups of a
// wave land in 16 distinct banks (2g+2e mod 32).
// ---------------------------------------------------------------------------
__global__ __launch_bounds__(256) void sample_kernel(
    const unsigned short* __restrict__ value,   // [Q][256] bf16
    const float* __restrict__ offattn,          // [Q][384] f32
    const float* __restrict__ refpts,           // [Q][4][2] f32
    unsigned short* __restrict__ sampled)       // [Q][256] bf16
{
    __shared__ int2 s_iw[64 * 65];

    const int tid   = threadIdx.x;
    const int qbase = blockIdx.x * QB;

    // ---------------- phase 1: softmax + tap prep ----------------
    {
        const int g  = tid >> 2;        // ql*8 + h  (0..63)
        const int l  = tid & 3;         // level
        const int ql = g >> 3, h = g & 7;
        const int q  = qbase + ql;
        const float* oa = offattn + (size_t)q * 384;

        // 4 logits of this (q,h,l)
        float4 lg = *(const float4*)(oa + 256 + h * 16 + l * 4);
        float m = fmaxf(fmaxf(lg.x, lg.y), fmaxf(lg.z, lg.w));
        m = fmaxf(m, __shfl_xor(m, 1));
        m = fmaxf(m, __shfl_xor(m, 2));
        float e0 = __expf(lg.x - m), e1 = __expf(lg.y - m),
              e2 = __expf(lg.z - m), e3 = __expf(lg.w - m);
        float s = e0 + e1 + e2 + e3;
        s += __shfl_xor(s, 1);
        s += __shfl_xor(s, 2);
        const float inv = 1.f / s;
        float aw[4] = {e0 * inv, e1 * inv, e2 * inv, e3 * inv};

        const float4 o01 = *(const float4*)(oa + h * 32 + l * 8);
        const float4 o23 = *(const float4*)(oa + h * 32 + l * 8 + 4);
        const float2 rp  = *(const float2*)(refpts + (size_t)q * 8 + l * 2);
        const int   SZ[4] = {128, 64, 32, 16};
        const int   ST[4] = {0, 16384, 20480, 21504};
        const float S = (float)SZ[l];
        const int   W_ = SZ[l], START = ST[l];
        const float oxs[4] = {o01.x, o01.z, o23.x, o23.z};
        const float oys[4] = {o01.y, o01.w, o23.y, o23.w};
        int2* dst = &s_iw[g * 65 + l * 16];
#pragma unroll
        for (int p = 0; p < 4; p++) {
            const float gx = (rp.x + oxs[p] / S) * S - 0.5f;
            const float gy = (rp.y + oys[p] / S) * S - 0.5f;
            const float x0f = floorf(gx), y0f = floorf(gy);
            const float lx = gx - x0f, ly = gy - y0f;
            const int x0 = (int)x0f, y0 = (int)y0f;
            const float a = aw[p];
#pragma unroll
            for (int tap = 0; tap < 4; tap++) {
                const int dx = tap & 1, dy = tap >> 1;
                const int xi = x0 + dx, yi = y0 + dy;
                const bool valid = (xi >= 0) & (xi < W_) & (yi >= 0) & (yi < W_);
                const float wx = dx ? lx : 1.f - lx;
                const float wy = dy ? ly : 1.f - ly;
                int2 r;
                r.x = valid ? (START + yi * W_ + xi) : 0;
                r.y = __float_as_int(valid ? wx * wy * a : 0.f);
                dst[p * 4 + tap] = r;
            }
        }
    }
    __syncthreads();

    // ---------------- phase 2: gather + accumulate ----------------
    {
        const int d8 = tid & 3;
        const int h  = (tid >> 2) & 7;
        const int ql = tid >> 5;
        const int q  = qbase + ql;
        const int g  = ql * 8 + h;
        const int2* iw = &s_iw[g * 65];
        const char* vb = (const char*)value + (h * 64 + d8 * 16);

        float acc[8] = {0.f, 0.f, 0.f, 0.f, 0.f, 0.f, 0.f, 0.f};
#pragma unroll 8
        for (int i = 0; i < 64; i++) {
            const int2 p = iw[i];
            const float w = __int_as_float(p.y);
            const u32x4 uv = *(const u32x4*)(vb + (size_t)(unsigned)p.x * 512);
#pragma unroll
            for (int r = 0; r < 4; r++) {
                const float lo = __uint_as_float(uv[r] << 16);
                const float hi = __uint_as_float(uv[r] & 0xffff0000u);
                acc[2 * r]     = fmaf(lo, w, acc[2 * r]);
                acc[2 * r + 1] = fmaf(hi, w, acc[2 * r + 1]);
            }
        }
        s16x8 o = pack8(make_float4(acc[0], acc[1], acc[2], acc[3]),
                        make_float4(acc[4], acc[5], acc[6], acc[7]));
        *(s16x8*)(sampled + (size_t)q * 256 + h * 32 + d8 * 8) = o;
    }
}

// ---------------------------------------------------------------------------
extern "C" void kernel_launch(void* const* d_in, const int* in_sizes, int n_in,
                              void* d_out, int out_size, void* d_ws, size_t ws_size,
                              hipStream_t stream) {
    const float* query  = (const float*)d_in[0];
    const float* refpts = (const float*)d_in[1];
    const float* input_flatten = (const float*)d_in[2];
    const float* W_off  = (const float*)d_in[5];
    const float* b_off  = (const float*)d_in[6];
    const float* W_attn = (const float*)d_in[7];
    const float* b_attn = (const float*)d_in[8];
    const float* W_val  = (const float*)d_in[9];
    const float* b_val  = (const float*)d_in[10];
    const float* W_out  = (const float*)d_in[11];
    const float* b_out  = (const float*)d_in[12];
    float* out = (float*)d_out;

    char* ws = (char*)d_ws;
    unsigned short* value   = (unsigned short*)ws;                         // Q*256 bf16
    float*          offattn = (float*)(ws + 11141120);                     // Q*384 f32
    unsigned short* sampled = (unsigned short*)(ws + 44564480);            // Q*256 bf16
    unsigned short* w16     = (unsigned short*)(ws + 55705600);            // 229376 bf16
    float*          bias_cat= (float*)(ws + 56164352);                     // 384 f32
    unsigned short* w16_val  = w16 + 98304;
    unsigned short* w16_out  = w16 + 163840;

    cvt_weights<<<225, 256, 0, stream>>>(W_off, W_attn, W_val, W_out, b_off, b_attn, w16, bias_cat);

    // value = input_flatten @ W_val^T + b_val  (bf16 out)
    gemm_mfma<256, false, true ><<<NBLK_M, 256, 0, stream>>>(input_flatten, w16_val, b_val, value, 256);
    // [offsets | attn logits] = query @ [W_off;W_attn]^T + bias_cat
    gemm_mfma<384, false, false><<<NBLK_M, 256, 0, stream>>>(query, w16, bias_cat, offattn, 384);
    // bilinear sampling + attention-weighted sum (bf16 in/out)
    sample_kernel<<<Q_TOTAL / QB, 256, 0, stream>>>(value, offattn, refpts, sampled);
    // out = sampled @ W_out^T + b_out
    gemm_mfma<256, true,  false><<<NBLK_M, 256, 0, stream>>>(sampled, w16_out, b_out, out, 256);
}

// Round 4
// 95.896 us; speedup vs baseline: 2.5420x; 1.0300x over previous
//
#include <hip/hip_runtime.h>
#include <math.h>

#define Q_TOTAL 21760
#define NBLK_M 340   // 21760 / 64
#define QB 8         // queries per sampling block

typedef short        s16x8 __attribute__((ext_vector_type(8)));
typedef __bf16       bfv8  __attribute__((ext_vector_type(8)));
typedef float        f32x4 __attribute__((ext_vector_type(4)));
typedef unsigned int u32x4 __attribute__((ext_vector_type(4)));

// pack 8 floats -> 8 bf16 (RNE; compiler emits v_cvt_pk_bf16_f32)
__device__ __forceinline__ s16x8 pack8(float4 a, float4 b) {
    bfv8 t;
    t[0] = (__bf16)a.x; t[1] = (__bf16)a.y; t[2] = (__bf16)a.z; t[3] = (__bf16)a.w;
    t[4] = (__bf16)b.x; t[5] = (__bf16)b.y; t[6] = (__bf16)b.z; t[7] = (__bf16)b.w;
    return __builtin_bit_cast(s16x8, t);
}

// ---------------------------------------------------------------------------
// Convert the 4 weight matrices to bf16 + build concat bias [b_off|b_attn].
// dst layout: [W_off 65536 | W_attn 32768 | W_val 65536 | W_out 65536]
// ---------------------------------------------------------------------------
__global__ __launch_bounds__(256) void cvt_weights(
    const float* __restrict__ Woff, const float* __restrict__ Wattn,
    const float* __restrict__ Wval, const float* __restrict__ Wout,
    const float* __restrict__ boff, const float* __restrict__ battn,
    unsigned short* __restrict__ dst, float* __restrict__ bias_cat)
{
    if (blockIdx.x == 224) {
        const int t = threadIdx.x;
        bias_cat[t] = boff[t];
        if (t < 128) bias_cat[256 + t] = battn[t];
        return;
    }
    const int e = blockIdx.x * 1024 + threadIdx.x * 4;
    const float* src; int base;
    if (e < 65536)       { src = Woff;  base = 0; }
    else if (e < 98304)  { src = Wattn; base = 65536; }
    else if (e < 163840) { src = Wval;  base = 98304; }
    else                 { src = Wout;  base = 163840; }
    float4 v = *(const float4*)(src + (e - base));
    ushort4 o;
    o.x = __builtin_bit_cast(unsigned short, (__bf16)v.x);
    o.y = __builtin_bit_cast(unsigned short, (__bf16)v.y);
    o.z = __builtin_bit_cast(unsigned short, (__bf16)v.z);
    o.w = __builtin_bit_cast(unsigned short, (__bf16)v.w);
    *(ushort4*)(dst + e) = o;
}

// ---------------------------------------------------------------------------
// MFMA bf16 GEMM: C[M][ldc] slab = A[M][256] @ W[colBase..colBase+127][256]^T
// BM=64, BN=128 slab, BK=32, 256 threads = 4 waves (2x2).
// Grid: (M/64, N/128).  LDS XOR-swizzled -> ds_read_b128 2-way (free).
// ---------------------------------------------------------------------------
template<bool A_BF16, bool C_BF16>
__global__ __launch_bounds__(256) void gemm_mfma(
    const void* __restrict__ Avoid,
    const unsigned short* __restrict__ W16,
    const float* __restrict__ bias,
    void* __restrict__ Cvoid,
    int ldc)
{
    constexpr int K = 256, BM = 64, BN = 128;
    constexpr int NB2 = BN / 2;          // 64 cols per wave-col
    constexpr int NF = NB2 / 16;         // 4 frags
    __shared__ unsigned short As[BM * 32];
    __shared__ unsigned short Bs[BN * 32];

    const int tid  = threadIdx.x;
    const int lane = tid & 63;
    const int wv   = tid >> 6;
    const int wr   = wv >> 1, wc = wv & 1;
    const int rowBase = blockIdx.x * BM;
    const int colBase = blockIdx.y * BN;

    const int sr    = tid >> 2;          // staging row 0..63
    const int skq   = (tid & 3) * 8;     // 8 elems per thread along K
    const int sslot = (tid & 3) * 16;    // byte slot within 64B row

    f32x4 acc[2][NF];
#pragma unroll
    for (int i = 0; i < 2; i++)
#pragma unroll
        for (int j = 0; j < NF; j++) acc[i][j] = (f32x4){0.f, 0.f, 0.f, 0.f};

    const size_t arow = (size_t)(rowBase + sr) * K;

    for (int kt = 0; kt < K; kt += 32) {
        s16x8 aval;
        if constexpr (A_BF16) {
            const unsigned short* A16 = (const unsigned short*)Avoid;
            aval = *(const s16x8*)(A16 + arow + kt + skq);
        } else {
            const float* A32 = (const float*)Avoid;
            const float* p = A32 + arow + kt + skq;
            aval = pack8(*(const float4*)p, *(const float4*)(p + 4));
        }
        s16x8 bval[2];
#pragma unroll
        for (int c = 0; c < 2; c++) {
            const unsigned short* p = W16 + (size_t)(colBase + c * 64 + sr) * K + kt + skq;
            bval[c] = *(const s16x8*)p;
        }
        __syncthreads();
        *(s16x8*)(As + (((sr * 64 + sslot) ^ ((sr & 7) << 4)) >> 1)) = aval;
#pragma unroll
        for (int c = 0; c < 2; c++) {
            const int row = c * 64 + sr;
            *(s16x8*)(Bs + (((row * 64 + sslot) ^ ((row & 7) << 4)) >> 1)) = bval[c];
        }
        __syncthreads();
        s16x8 af[2];
#pragma unroll
        for (int mi = 0; mi < 2; mi++) {
            const int row = wr * 32 + mi * 16 + (lane & 15);
            af[mi] = *(const s16x8*)(As + (((row * 64 + (lane >> 4) * 16) ^ ((row & 7) << 4)) >> 1));
        }
#pragma unroll
        for (int ni = 0; ni < NF; ni++) {
            const int row = wc * NB2 + ni * 16 + (lane & 15);
            s16x8 bfrag = *(const s16x8*)(Bs + (((row * 64 + (lane >> 4) * 16) ^ ((row & 7) << 4)) >> 1));
#pragma unroll
            for (int mi = 0; mi < 2; mi++)
                acc[mi][ni] = __builtin_amdgcn_mfma_f32_16x16x32_bf16(af[mi], bfrag, acc[mi][ni], 0, 0, 0);
        }
    }

#pragma unroll
    for (int ni = 0; ni < NF; ni++) {
        const int col = colBase + wc * NB2 + ni * 16 + (lane & 15);
        const float bv = bias[col];
#pragma unroll
        for (int mi = 0; mi < 2; mi++) {
            const int r0 = rowBase + wr * 32 + mi * 16 + (lane >> 4) * 4;
#pragma unroll
            for (int j = 0; j < 4; j++) {
                const float v = acc[mi][ni][j] + bv;
                if constexpr (C_BF16) {
                    ((unsigned short*)Cvoid)[(size_t)(r0 + j) * ldc + col] =
                        __builtin_bit_cast(unsigned short, (__bf16)v);
                } else {
                    ((float*)Cvoid)[(size_t)(r0 + j) * ldc + col] = v;
                }
            }
        }
    }
}

// ---------------------------------------------------------------------------
// Sampling: block = 8 queries x 32 threads (256 threads).
// Phase 1: softmax + per-tap packed (idx<<16 | bf16(weight)) u32 into LDS.
// Phase 2: tid = ql*32 + h*4 + d8; each thread gathers 16B/tap.
// s_iw stride 65 u32 -> group g at bank g (mod 32): P2 reads conflict-free
// (4 d8 lanes broadcast), P1 writes 2-way (free).
// ---------------------------------------------------------------------------
__global__ __launch_bounds__(256) void sample_kernel(
    const unsigned short* __restrict__ value,   // [Q][256] bf16
    const float* __restrict__ offattn,          // [Q][384] f32
    const float* __restrict__ refpts,           // [Q][4][2] f32
    unsigned short* __restrict__ sampled)       // [Q][256] bf16
{
    __shared__ unsigned s_iw[64 * 65];

    const int tid   = threadIdx.x;
    const int qbase = blockIdx.x * QB;

    // ---------------- phase 1: softmax + tap prep ----------------
    {
        const int g  = tid >> 2;        // ql*8 + h  (0..63)
        const int l  = tid & 3;         // level
        const int ql = g >> 3, h = g & 7;
        const int q  = qbase + ql;
        const float* oa = offattn + (size_t)q * 384;

        float4 lg = *(const float4*)(oa + 256 + h * 16 + l * 4);
        float m = fmaxf(fmaxf(lg.x, lg.y), fmaxf(lg.z, lg.w));
        m = fmaxf(m, __shfl_xor(m, 1));
        m = fmaxf(m, __shfl_xor(m, 2));
        float e0 = __expf(lg.x - m), e1 = __expf(lg.y - m),
              e2 = __expf(lg.z - m), e3 = __expf(lg.w - m);
        float s = e0 + e1 + e2 + e3;
        s += __shfl_xor(s, 1);
        s += __shfl_xor(s, 2);
        const float inv = 1.f / s;
        float aw[4] = {e0 * inv, e1 * inv, e2 * inv, e3 * inv};

        const float4 o01 = *(const float4*)(oa + h * 32 + l * 8);
        const float4 o23 = *(const float4*)(oa + h * 32 + l * 8 + 4);
        const float2 rp  = *(const float2*)(refpts + (size_t)q * 8 + l * 2);
        const int   SZ[4] = {128, 64, 32, 16};
        const int   ST[4] = {0, 16384, 20480, 21504};
        const float S = (float)SZ[l];
        const int   W_ = SZ[l], START = ST[l];
        const float oxs[4] = {o01.x, o01.z, o23.x, o23.z};
        const float oys[4] = {o01.y, o01.w, o23.y, o23.w};
        unsigned* dst = &s_iw[g * 65 + l * 16];
#pragma unroll
        for (int p = 0; p < 4; p++) {
            const float gx = (rp.x + oxs[p] / S) * S - 0.5f;
            const float gy = (rp.y + oys[p] / S) * S - 0.5f;
            const float x0f = floorf(gx), y0f = floorf(gy);
            const float lx = gx - x0f, ly = gy - y0f;
            const int x0 = (int)x0f, y0 = (int)y0f;
            const float a = aw[p];
#pragma unroll
            for (int tap = 0; tap < 4; tap++) {
                const int dx = tap & 1, dy = tap >> 1;
                const int xi = x0 + dx, yi = y0 + dy;
                const bool valid = (xi >= 0) & (xi < W_) & (yi >= 0) & (yi < W_);
                const float wx = dx ? lx : 1.f - lx;
                const float wy = dy ? ly : 1.f - ly;
                const float wgt = valid ? wx * wy * a : 0.f;
                const unsigned idx = valid ? (unsigned)(START + yi * W_ + xi) : 0u;
                const unsigned wb = (unsigned)__builtin_bit_cast(unsigned short, (__bf16)wgt);
                dst[p * 4 + tap] = (idx << 16) | wb;
            }
        }
    }
    __syncthreads();

    // ---------------- phase 2: gather + accumulate ----------------
    {
        const int d8 = tid & 3;
        const int h  = (tid >> 2) & 7;
        const int ql = tid >> 5;
        const int q  = qbase + ql;
        const int g  = ql * 8 + h;
        const unsigned* iw = &s_iw[g * 65];
        const char* vb = (const char*)value + (h * 64 + d8 * 16);

        float acc[8] = {0.f, 0.f, 0.f, 0.f, 0.f, 0.f, 0.f, 0.f};
#pragma unroll 8
        for (int i = 0; i < 64; i++) {
            const unsigned u = iw[i];
            const float w = __uint_as_float(u << 16);           // bf16 -> f32
            const unsigned ofs = (u >> 16) << 9;                // idx * 512 B
            const u32x4 uv = *(const u32x4*)(vb + ofs);
#pragma unroll
            for (int r = 0; r < 4; r++) {
                const float lo = __uint_as_float(uv[r] << 16);
                const float hi = __uint_as_float(uv[r] & 0xffff0000u);
                acc[2 * r]     = fmaf(lo, w, acc[2 * r]);
                acc[2 * r + 1] = fmaf(hi, w, acc[2 * r + 1]);
            }
        }
        s16x8 o = pack8(make_float4(acc[0], acc[1], acc[2], acc[3]),
                        make_float4(acc[4], acc[5], acc[6], acc[7]));
        *(s16x8*)(sampled + (size_t)q * 256 + h * 32 + d8 * 8) = o;
    }
}

// ---------------------------------------------------------------------------
extern "C" void kernel_launch(void* const* d_in, const int* in_sizes, int n_in,
                              void* d_out, int out_size, void* d_ws, size_t ws_size,
                              hipStream_t stream) {
    const float* query  = (const float*)d_in[0];
    const float* refpts = (const float*)d_in[1];
    const float* input_flatten = (const float*)d_in[2];
    const float* W_off  = (const float*)d_in[5];
    const float* b_off  = (const float*)d_in[6];
    const float* W_attn = (const float*)d_in[7];
    const float* b_attn = (const float*)d_in[8];
    const float* W_val  = (const float*)d_in[9];
    const float* b_val  = (const float*)d_in[10];
    const float* W_out  = (const float*)d_in[11];
    const float* b_out  = (const float*)d_in[12];
    float* out = (float*)d_out;

    char* ws = (char*)d_ws;
    unsigned short* value   = (unsigned short*)ws;                         // Q*256 bf16
    float*          offattn = (float*)(ws + 11141120);                     // Q*384 f32
    unsigned short* sampled = (unsigned short*)(ws + 44564480);            // Q*256 bf16
    unsigned short* w16     = (unsigned short*)(ws + 55705600);            // 229376 bf16
    float*          bias_cat= (float*)(ws + 56164352);                     // 384 f32
    unsigned short* w16_val  = w16 + 98304;
    unsigned short* w16_out  = w16 + 163840;

    cvt_weights<<<225, 256, 0, stream>>>(W_off, W_attn, W_val, W_out, b_off, b_attn, w16, bias_cat);

    // value = input_flatten @ W_val^T + b_val  (bf16 out)
    gemm_mfma<false, true ><<<dim3(NBLK_M, 2), 256, 0, stream>>>(input_flatten, w16_val, b_val, value, 256);
    // [offsets | attn logits] = query @ [W_off;W_attn]^T + bias_cat
    gemm_mfma<false, false><<<dim3(NBLK_M, 3), 256, 0, stream>>>(query, w16, bias_cat, offattn, 384);
    // bilinear sampling + attention-weighted sum (bf16 in/out)
    sample_kernel<<<Q_TOTAL / QB, 256, 0, stream>>>(value, offattn, refpts, sampled);
    // out = sampled @ W_out^T + b_out
    gemm_mfma<true,  false><<<dim3(NBLK_M, 2), 256, 0, stream>>>(sampled, w16_out, b_out, out, 256);
}

// Round 5
// 83.124 us; speedup vs baseline: 2.9326x; 1.1536x over previous
//
#include <hip/hip_runtime.h>
#include <math.h>

#define Q_TOTAL 21760
#define NBLK_M 340   // 21760 / 64
#define QB 16        // queries per sampling block
#define HEAD_IMG_BYTES 1392640   // 21760 * 32 * 2  (one head's transposed image)

typedef short        s16x8 __attribute__((ext_vector_type(8)));
typedef __bf16       bfv8  __attribute__((ext_vector_type(8)));
typedef float        f32x4 __attribute__((ext_vector_type(4)));
typedef float        f32x2 __attribute__((ext_vector_type(2)));
typedef unsigned int u32x4 __attribute__((ext_vector_type(4)));

// pack 8 floats -> 8 bf16 (RNE; compiler emits v_cvt_pk_bf16_f32)
__device__ __forceinline__ s16x8 pack8(float4 a, float4 b) {
    bfv8 t;
    t[0] = (__bf16)a.x; t[1] = (__bf16)a.y; t[2] = (__bf16)a.z; t[3] = (__bf16)a.w;
    t[4] = (__bf16)b.x; t[5] = (__bf16)b.y; t[6] = (__bf16)b.z; t[7] = (__bf16)b.w;
    return __builtin_bit_cast(s16x8, t);
}

__device__ __forceinline__ unsigned pack2bf(float lo, float hi) {
    unsigned a = (unsigned)__builtin_bit_cast(unsigned short, (__bf16)lo);
    unsigned b = (unsigned)__builtin_bit_cast(unsigned short, (__bf16)hi);
    return (b << 16) | a;
}

// ---------------------------------------------------------------------------
// Convert the 4 weight matrices to bf16 + build concat bias [b_off|b_attn].
// dst layout: [W_off 65536 | W_attn 32768 | W_val 65536 | W_out 65536]
// ---------------------------------------------------------------------------
__global__ __launch_bounds__(256) void cvt_weights(
    const float* __restrict__ Woff, const float* __restrict__ Wattn,
    const float* __restrict__ Wval, const float* __restrict__ Wout,
    const float* __restrict__ boff, const float* __restrict__ battn,
    unsigned short* __restrict__ dst, float* __restrict__ bias_cat)
{
    if (blockIdx.x == 224) {
        const int t = threadIdx.x;
        bias_cat[t] = boff[t];
        if (t < 128) bias_cat[256 + t] = battn[t];
        return;
    }
    const int e = blockIdx.x * 1024 + threadIdx.x * 4;
    const float* src; int base;
    if (e < 65536)       { src = Woff;  base = 0; }
    else if (e < 98304)  { src = Wattn; base = 65536; }
    else if (e < 163840) { src = Wval;  base = 98304; }
    else                 { src = Wout;  base = 163840; }
    float4 v = *(const float4*)(src + (e - base));
    ushort4 o;
    o.x = __builtin_bit_cast(unsigned short, (__bf16)v.x);
    o.y = __builtin_bit_cast(unsigned short, (__bf16)v.y);
    o.z = __builtin_bit_cast(unsigned short, (__bf16)v.z);
    o.w = __builtin_bit_cast(unsigned short, (__bf16)v.w);
    *(ushort4*)(dst + e) = o;
}

// ---------------------------------------------------------------------------
// MFMA bf16 GEMM: C[M][ldc] slab = A[M][256] @ W[colBase..colBase+127][256]^T
// BM=64, BN=128 slab, BK=32, 256 threads = 4 waves (2x2).
// VT: write C transposed per-head: value_t[col>>5][row][col&31] (bf16).
// ---------------------------------------------------------------------------
template<bool A_BF16, bool C_BF16, bool VT>
__global__ __launch_bounds__(256) void gemm_mfma(
    const void* __restrict__ Avoid,
    const unsigned short* __restrict__ W16,
    const float* __restrict__ bias,
    void* __restrict__ Cvoid,
    int ldc)
{
    constexpr int K = 256, BM = 64, BN = 128;
    constexpr int NB2 = BN / 2;          // 64 cols per wave-col
    constexpr int NF = NB2 / 16;         // 4 frags
    __shared__ unsigned short As[BM * 32];
    __shared__ unsigned short Bs[BN * 32];

    const int tid  = threadIdx.x;
    const int lane = tid & 63;
    const int wv   = tid >> 6;
    const int wr   = wv >> 1, wc = wv & 1;
    const int rowBase = blockIdx.x * BM;
    const int colBase = blockIdx.y * BN;

    const int sr    = tid >> 2;          // staging row 0..63
    const int skq   = (tid & 3) * 8;     // 8 elems per thread along K
    const int sslot = (tid & 3) * 16;    // byte slot within 64B row

    f32x4 acc[2][NF];
#pragma unroll
    for (int i = 0; i < 2; i++)
#pragma unroll
        for (int j = 0; j < NF; j++) acc[i][j] = (f32x4){0.f, 0.f, 0.f, 0.f};

    const size_t arow = (size_t)(rowBase + sr) * K;

    for (int kt = 0; kt < K; kt += 32) {
        s16x8 aval;
        if constexpr (A_BF16) {
            const unsigned short* A16 = (const unsigned short*)Avoid;
            aval = *(const s16x8*)(A16 + arow + kt + skq);
        } else {
            const float* A32 = (const float*)Avoid;
            const float* p = A32 + arow + kt + skq;
            aval = pack8(*(const float4*)p, *(const float4*)(p + 4));
        }
        s16x8 bval[2];
#pragma unroll
        for (int c = 0; c < 2; c++) {
            const unsigned short* p = W16 + (size_t)(colBase + c * 64 + sr) * K + kt + skq;
            bval[c] = *(const s16x8*)p;
        }
        __syncthreads();
        *(s16x8*)(As + (((sr * 64 + sslot) ^ ((sr & 7) << 4)) >> 1)) = aval;
#pragma unroll
        for (int c = 0; c < 2; c++) {
            const int row = c * 64 + sr;
            *(s16x8*)(Bs + (((row * 64 + sslot) ^ ((row & 7) << 4)) >> 1)) = bval[c];
        }
        __syncthreads();
        s16x8 af[2];
#pragma unroll
        for (int mi = 0; mi < 2; mi++) {
            const int row = wr * 32 + mi * 16 + (lane & 15);
            af[mi] = *(const s16x8*)(As + (((row * 64 + (lane >> 4) * 16) ^ ((row & 7) << 4)) >> 1));
        }
#pragma unroll
        for (int ni = 0; ni < NF; ni++) {
            const int row = wc * NB2 + ni * 16 + (lane & 15);
            s16x8 bfrag = *(const s16x8*)(Bs + (((row * 64 + (lane >> 4) * 16) ^ ((row & 7) << 4)) >> 1));
#pragma unroll
            for (int mi = 0; mi < 2; mi++)
                acc[mi][ni] = __builtin_amdgcn_mfma_f32_16x16x32_bf16(af[mi], bfrag, acc[mi][ni], 0, 0, 0);
        }
    }

#pragma unroll
    for (int ni = 0; ni < NF; ni++) {
        const int col = colBase + wc * NB2 + ni * 16 + (lane & 15);
        const float bv = bias[col];
#pragma unroll
        for (int mi = 0; mi < 2; mi++) {
            const int r0 = rowBase + wr * 32 + mi * 16 + (lane >> 4) * 4;
#pragma unroll
            for (int j = 0; j < 4; j++) {
                const float v = acc[mi][ni][j] + bv;
                if constexpr (VT) {
                    // value_t[h][pix][32], h = col>>5
                    ((unsigned short*)Cvoid)[((size_t)(col >> 5) * Q_TOTAL + (r0 + j)) * 32 + (col & 31)] =
                        __builtin_bit_cast(unsigned short, (__bf16)v);
                } else if constexpr (C_BF16) {
                    ((unsigned short*)Cvoid)[(size_t)(r0 + j) * ldc + col] =
                        __builtin_bit_cast(unsigned short, (__bf16)v);
                } else {
                    ((float*)Cvoid)[(size_t)(r0 + j) * ldc + col] = v;
                }
            }
        }
    }
}

// ---------------------------------------------------------------------------
// Sampling: block = 16 queries x 2 heads (256 threads).
// bid = qtile*4 + headpair  ->  bid%8 in {hp, hp+4}: each XCD touches only
// 2 heads' value slice (2.78 MB < 4 MB L2) in the transposed layout.
// Phase 1 (tid = q*16 + h*8 + l*2 + ph): softmax over 8-lane group, then per
// point pack {base_y0, base_y1, bf16(wxA,wxB), bf16(a*wy0, a*wy1)} -> LDS.
// Phase 2 (tid = q*16 + h*8 + xc*4 + d8): per point 2 loads of 16B; the 8-lane
// group covers 128 B = both x-corners x 32 dims; xor(4) reduce combines corners.
// ---------------------------------------------------------------------------
__global__ __launch_bounds__(256) void sample_kernel(
    const unsigned short* __restrict__ value_t,  // [8][Q][32] bf16
    const float* __restrict__ offattn,           // [Q][384] f32
    const float* __restrict__ refpts,            // [Q][4][2] f32
    unsigned short* __restrict__ sampled)        // [Q][256] bf16
{
    __shared__ unsigned s_iw[32 * 68];   // 32 groups, 16 points * int4, stride 68 words

    const int tid   = threadIdx.x;
    const int qt    = blockIdx.x >> 2;
    const int hp    = blockIdx.x & 3;
    const int qbase = qt * QB;

    // ---------------- phase 1 ----------------
    {
        const int q  = tid >> 4;
        const int h  = (tid >> 3) & 1;
        const int l  = (tid >> 1) & 3;
        const int ph = tid & 1;
        const int H  = hp * 2 + h;
        const int g  = tid >> 3;         // q*2 + h
        const float* oa = offattn + (size_t)(qbase + q) * 384;

        f32x2 lg = __builtin_nontemporal_load((const f32x2*)(oa + 256 + H * 16 + l * 4 + ph * 2));
        float m = fmaxf(lg[0], lg[1]);
        m = fmaxf(m, __shfl_xor(m, 1));
        m = fmaxf(m, __shfl_xor(m, 2));
        m = fmaxf(m, __shfl_xor(m, 4));
        float e0 = __expf(lg[0] - m), e1 = __expf(lg[1] - m);
        float s = e0 + e1;
        s += __shfl_xor(s, 1);
        s += __shfl_xor(s, 2);
        s += __shfl_xor(s, 4);
        const float inv = 1.f / s;
        const float aw2[2] = {e0 * inv, e1 * inv};

        f32x4 off4 = __builtin_nontemporal_load((const f32x4*)(oa + H * 32 + l * 8 + ph * 4));
        f32x2 rp = *(const f32x2*)(refpts + (size_t)(qbase + q) * 8 + l * 2);

        const int   SZ[4] = {128, 64, 32, 16};
        const int   ST[4] = {0, 16384, 20480, 21504};
        const int   W_ = SZ[l], START = ST[l];
        const float S = (float)W_;

        unsigned* dst = &s_iw[g * 68 + (l * 4 + ph * 2) * 4];
#pragma unroll
        for (int c = 0; c < 2; c++) {
            const float ox = off4[c * 2], oy = off4[c * 2 + 1];
            const float a = aw2[c];
            const float gx = fmaf(rp[0], S, ox) - 0.5f;
            const float gy = fmaf(rp[1], S, oy) - 0.5f;
            const float x0f = floorf(gx), y0f = floorf(gy);
            const float lx = gx - x0f, ly = gy - y0f;
            const int x0 = (int)x0f, y0 = (int)y0f;
            // x pair, clamped to [0, W-2]; shift weights to match clamp
            const int xs  = min(max(x0, 0), W_ - 2);
            const int sft = xs - x0;
            const float wx0 = (x0 >= 0 && x0 < W_) ? (1.f - lx) : 0.f;
            const float wx1 = (x0 + 1 >= 0 && x0 + 1 < W_) ? lx : 0.f;
            const float wxA = (sft == 0) ? wx0 : ((sft == 1) ? wx1 : 0.f);
            const float wxB = (sft == 0) ? wx1 : ((sft == -1) ? wx0 : 0.f);
            // y rows independent: clamp address, zero weight
            const int y1 = y0 + 1;
            const int y0c = min(max(y0, 0), W_ - 1);
            const int y1c = min(max(y1, 0), W_ - 1);
            const float wy0 = ((y0 >= 0) && (y0 < W_)) ? (1.f - ly) * a : 0.f;
            const float wy1 = ((y1 >= 0) && (y1 < W_)) ? ly * a : 0.f;
            u32x4 rec;
            rec[0] = (unsigned)((START + y0c * W_ + xs) * 64);
            rec[1] = (unsigned)((START + y1c * W_ + xs) * 64);
            rec[2] = pack2bf(wxA, wxB);
            rec[3] = pack2bf(wy0, wy1);
            *(u32x4*)(dst + c * 4) = rec;
        }
    }
    __syncthreads();

    // ---------------- phase 2 ----------------
    {
        const int d8 = tid & 3;
        const int xc = (tid >> 2) & 1;
        const int g  = tid >> 3;          // q*2 + h
        const int q  = g >> 1;
        const int h  = g & 1;
        const int H  = hp * 2 + h;
        const char* hb = (const char*)value_t + (size_t)H * HEAD_IMG_BYTES + xc * 64 + d8 * 16;
        const unsigned* iw = &s_iw[g * 68];

        float acc[8] = {0.f, 0.f, 0.f, 0.f, 0.f, 0.f, 0.f, 0.f};
#pragma unroll
        for (int p = 0; p < 16; p++) {
            const u32x4 t = *(const u32x4*)(iw + p * 4);
            const float wx = __uint_as_float(xc ? (t[2] & 0xffff0000u) : (t[2] << 16));
            const float w0 = __uint_as_float(t[3] << 16) * wx;
            const float w1 = __uint_as_float(t[3] & 0xffff0000u) * wx;
            const u32x4 v0 = *(const u32x4*)(hb + t[0]);
            const u32x4 v1 = *(const u32x4*)(hb + t[1]);
#pragma unroll
            for (int r = 0; r < 4; r++) {
                acc[2 * r]     = fmaf(__uint_as_float(v0[r] << 16),          w0, acc[2 * r]);
                acc[2 * r + 1] = fmaf(__uint_as_float(v0[r] & 0xffff0000u), w0, acc[2 * r + 1]);
                acc[2 * r]     = fmaf(__uint_as_float(v1[r] << 16),          w1, acc[2 * r]);
                acc[2 * r + 1] = fmaf(__uint_as_float(v1[r] & 0xffff0000u), w1, acc[2 * r + 1]);
            }
        }
#pragma unroll
        for (int j = 0; j < 8; j++) acc[j] += __shfl_xor(acc[j], 4);

        if (xc == 0) {
            s16x8 o = pack8(make_float4(acc[0], acc[1], acc[2], acc[3]),
                            make_float4(acc[4], acc[5], acc[6], acc[7]));
            *(s16x8*)(sampled + (size_t)(qbase + q) * 256 + H * 32 + d8 * 8) = o;
        }
    }
}

// ---------------------------------------------------------------------------
extern "C" void kernel_launch(void* const* d_in, const int* in_sizes, int n_in,
                              void* d_out, int out_size, void* d_ws, size_t ws_size,
                              hipStream_t stream) {
    const float* query  = (const float*)d_in[0];
    const float* refpts = (const float*)d_in[1];
    const float* input_flatten = (const float*)d_in[2];
    const float* W_off  = (const float*)d_in[5];
    const float* b_off  = (const float*)d_in[6];
    const float* W_attn = (const float*)d_in[7];
    const float* b_attn = (const float*)d_in[8];
    const float* W_val  = (const float*)d_in[9];
    const float* b_val  = (const float*)d_in[10];
    const float* W_out  = (const float*)d_in[11];
    const float* b_out  = (const float*)d_in[12];
    float* out = (float*)d_out;

    char* ws = (char*)d_ws;
    unsigned short* value_t = (unsigned short*)ws;                         // 8*Q*32 bf16
    float*          offattn = (float*)(ws + 11141120);                     // Q*384 f32
    unsigned short* sampled = (unsigned short*)(ws + 44564480);            // Q*256 bf16
    unsigned short* w16     = (unsigned short*)(ws + 55705600);            // 229376 bf16
    float*          bias_cat= (float*)(ws + 56164352);                     // 384 f32
    unsigned short* w16_val  = w16 + 98304;
    unsigned short* w16_out  = w16 + 163840;

    cvt_weights<<<225, 256, 0, stream>>>(W_off, W_attn, W_val, W_out, b_off, b_attn, w16, bias_cat);

    // value_t[h][pix][32] = (input_flatten @ W_val^T + b_val) transposed per head
    gemm_mfma<false, true , true ><<<dim3(NBLK_M, 2), 256, 0, stream>>>(input_flatten, w16_val, b_val, value_t, 256);
    // [offsets | attn logits] = query @ [W_off;W_attn]^T + bias_cat
    gemm_mfma<false, false, false><<<dim3(NBLK_M, 3), 256, 0, stream>>>(query, w16, bias_cat, offattn, 384);
    // bilinear sampling + attention-weighted sum
    sample_kernel<<<dim3((Q_TOTAL / QB) * 4), 256, 0, stream>>>(value_t, offattn, refpts, sampled);
    // out = sampled @ W_out^T + b_out
    gemm_mfma<true,  false, false><<<dim3(NBLK_M, 2), 256, 0, stream>>>(sampled, w16_out, b_out, out, 256);
}

// Round 7
// 82.917 us; speedup vs baseline: 2.9399x; 1.0025x over previous
//
#include <hip/hip_runtime.h>
#include <math.h>

#define Q_TOTAL 21760
#define NBLK_M 340   // 21760 / 64
#define QB 16        // queries per sampling block
#define HEAD_IMG_BYTES 1392640   // 21760 * 32 * 2  (one head's transposed image, f16)

typedef _Float16     f16;
typedef short        s16x8 __attribute__((ext_vector_type(8)));
typedef f16          f16x8 __attribute__((ext_vector_type(8)));
typedef __bf16       bfv8  __attribute__((ext_vector_type(8)));
typedef float        f32x4 __attribute__((ext_vector_type(4)));
typedef float        f32x2 __attribute__((ext_vector_type(2)));
typedef unsigned int u32x4 __attribute__((ext_vector_type(4)));

// pack 8 floats -> 8 bf16 (RNE; compiler emits v_cvt_pk_bf16_f32)
__device__ __forceinline__ s16x8 pack8(float4 a, float4 b) {
    bfv8 t;
    t[0] = (__bf16)a.x; t[1] = (__bf16)a.y; t[2] = (__bf16)a.z; t[3] = (__bf16)a.w;
    t[4] = (__bf16)b.x; t[5] = (__bf16)b.y; t[6] = (__bf16)b.z; t[7] = (__bf16)b.w;
    return __builtin_bit_cast(s16x8, t);
}

__device__ __forceinline__ unsigned pack2bf(float lo, float hi) {
    unsigned a = (unsigned)__builtin_bit_cast(unsigned short, (__bf16)lo);
    unsigned b = (unsigned)__builtin_bit_cast(unsigned short, (__bf16)hi);
    return (b << 16) | a;
}

// ---------------------------------------------------------------------------
// Convert the 4 weight matrices to bf16 + build concat bias [b_off|b_attn].
// dst layout: [W_off 65536 | W_attn 32768 | W_val 65536 | W_out 65536]
// ---------------------------------------------------------------------------
__global__ __launch_bounds__(256) void cvt_weights(
    const float* __restrict__ Woff, const float* __restrict__ Wattn,
    const float* __restrict__ Wval, const float* __restrict__ Wout,
    const float* __restrict__ boff, const float* __restrict__ battn,
    unsigned short* __restrict__ dst, float* __restrict__ bias_cat)
{
    if (blockIdx.x == 224) {
        const int t = threadIdx.x;
        bias_cat[t] = boff[t];
        if (t < 128) bias_cat[256 + t] = battn[t];
        return;
    }
    const int e = blockIdx.x * 1024 + threadIdx.x * 4;
    const float* src; int base;
    if (e < 65536)       { src = Woff;  base = 0; }
    else if (e < 98304)  { src = Wattn; base = 65536; }
    else if (e < 163840) { src = Wval;  base = 98304; }
    else                 { src = Wout;  base = 163840; }
    float4 v = *(const float4*)(src + (e - base));
    ushort4 o;
    o.x = __builtin_bit_cast(unsigned short, (__bf16)v.x);
    o.y = __builtin_bit_cast(unsigned short, (__bf16)v.y);
    o.z = __builtin_bit_cast(unsigned short, (__bf16)v.z);
    o.w = __builtin_bit_cast(unsigned short, (__bf16)v.w);
    *(ushort4*)(dst + e) = o;
}

// ---------------------------------------------------------------------------
// MFMA bf16 GEMM: C[M][ldc] slab = A[M][256] @ W[colBase..colBase+127][256]^T
// BM=64, BN=128 slab, BK=32, 256 threads = 4 waves (2x2).
// VT: write C transposed per-head as f16: value_t[col>>5][row][col&31].
// ---------------------------------------------------------------------------
template<bool A_BF16, bool C_BF16, bool VT>
__global__ __launch_bounds__(256) void gemm_mfma(
    const void* __restrict__ Avoid,
    const unsigned short* __restrict__ W16,
    const float* __restrict__ bias,
    void* __restrict__ Cvoid,
    int ldc)
{
    constexpr int K = 256, BM = 64, BN = 128;
    constexpr int NB2 = BN / 2;          // 64 cols per wave-col
    constexpr int NF = NB2 / 16;         // 4 frags
    __shared__ unsigned short As[BM * 32];
    __shared__ unsigned short Bs[BN * 32];

    const int tid  = threadIdx.x;
    const int lane = tid & 63;
    const int wv   = tid >> 6;
    const int wr   = wv >> 1, wc = wv & 1;
    const int rowBase = blockIdx.x * BM;
    const int colBase = blockIdx.y * BN;

    const int sr    = tid >> 2;          // staging row 0..63
    const int skq   = (tid & 3) * 8;     // 8 elems per thread along K
    const int sslot = (tid & 3) * 16;    // byte slot within 64B row

    f32x4 acc[2][NF];
#pragma unroll
    for (int i = 0; i < 2; i++)
#pragma unroll
        for (int j = 0; j < NF; j++) acc[i][j] = (f32x4){0.f, 0.f, 0.f, 0.f};

    const size_t arow = (size_t)(rowBase + sr) * K;

    for (int kt = 0; kt < K; kt += 32) {
        s16x8 aval;
        if constexpr (A_BF16) {
            const unsigned short* A16 = (const unsigned short*)Avoid;
            aval = *(const s16x8*)(A16 + arow + kt + skq);
        } else {
            const float* A32 = (const float*)Avoid;
            const float* p = A32 + arow + kt + skq;
            aval = pack8(*(const float4*)p, *(const float4*)(p + 4));
        }
        s16x8 bval[2];
#pragma unroll
        for (int c = 0; c < 2; c++) {
            const unsigned short* p = W16 + (size_t)(colBase + c * 64 + sr) * K + kt + skq;
            bval[c] = *(const s16x8*)p;
        }
        __syncthreads();
        *(s16x8*)(As + (((sr * 64 + sslot) ^ ((sr & 7) << 4)) >> 1)) = aval;
#pragma unroll
        for (int c = 0; c < 2; c++) {
            const int row = c * 64 + sr;
            *(s16x8*)(Bs + (((row * 64 + sslot) ^ ((row & 7) << 4)) >> 1)) = bval[c];
        }
        __syncthreads();
        s16x8 af[2];
#pragma unroll
        for (int mi = 0; mi < 2; mi++) {
            const int row = wr * 32 + mi * 16 + (lane & 15);
            af[mi] = *(const s16x8*)(As + (((row * 64 + (lane >> 4) * 16) ^ ((row & 7) << 4)) >> 1));
        }
#pragma unroll
        for (int ni = 0; ni < NF; ni++) {
            const int row = wc * NB2 + ni * 16 + (lane & 15);
            s16x8 bfrag = *(const s16x8*)(Bs + (((row * 64 + (lane >> 4) * 16) ^ ((row & 7) << 4)) >> 1));
#pragma unroll
            for (int mi = 0; mi < 2; mi++)
                acc[mi][ni] = __builtin_amdgcn_mfma_f32_16x16x32_bf16(af[mi], bfrag, acc[mi][ni], 0, 0, 0);
        }
    }

#pragma unroll
    for (int ni = 0; ni < NF; ni++) {
        const int col = colBase + wc * NB2 + ni * 16 + (lane & 15);
        const float bv = bias[col];
#pragma unroll
        for (int mi = 0; mi < 2; mi++) {
            const int r0 = rowBase + wr * 32 + mi * 16 + (lane >> 4) * 4;
#pragma unroll
            for (int j = 0; j < 4; j++) {
                const float v = acc[mi][ni][j] + bv;
                if constexpr (VT) {
                    // value_t[h][pix][32] f16, h = col>>5
                    ((f16*)Cvoid)[((size_t)(col >> 5) * Q_TOTAL + (r0 + j)) * 32 + (col & 31)] = (f16)v;
                } else if constexpr (C_BF16) {
                    ((unsigned short*)Cvoid)[(size_t)(r0 + j) * ldc + col] =
                        __builtin_bit_cast(unsigned short, (__bf16)v);
                } else {
                    ((float*)Cvoid)[(size_t)(r0 + j) * ldc + col] = v;
                }
            }
        }
    }
}

// ---------------------------------------------------------------------------
// Sampling: block = 16 queries x 2 heads (256 threads).
// bid = qtile*4 + headpair -> bid%8 in {hp, hp+4}: each XCD touches only
// 2 heads' value slice (2.78 MB < 4 MB L2) in the transposed f16 layout.
// Phase 1 (tid = q*16 + h*8 + l*2 + ph): softmax over 8-lane group, then per
// point pack {base_y0, base_y1, bf16(wxA,wxB), bf16(a*wy0, a*wy1)} -> LDS.
// Phase 2 (tid = q*16 + h*8 + xc*4 + d8): per point 2 loads of 16B f16;
// fmaf((float)h16, w, acc) fuses to v_fma_mix_f32 (no unpack ops);
// xor(4) reduce combines the two x-corners.
// ---------------------------------------------------------------------------
__global__ __launch_bounds__(256) void sample_kernel(
    const f16* __restrict__ value_t,             // [8][Q][32] f16
    const float* __restrict__ offattn,           // [Q][384] f32
    const float* __restrict__ refpts,            // [Q][4][2] f32
    unsigned short* __restrict__ sampled)        // [Q][256] bf16
{
    __shared__ unsigned s_iw[32 * 68];   // 32 groups, 16 points * int4, stride 68 words

    const int tid   = threadIdx.x;
    const int qt    = blockIdx.x >> 2;
    const int hp    = blockIdx.x & 3;
    const int qbase = qt * QB;

    // ---------------- phase 1 ----------------
    {
        const int q  = tid >> 4;
        const int h  = (tid >> 3) & 1;
        const int l  = (tid >> 1) & 3;
        const int ph = tid & 1;
        const int H  = hp * 2 + h;
        const int g  = tid >> 3;         // q*2 + h
        const float* oa = offattn + (size_t)(qbase + q) * 384;

        f32x2 lg = __builtin_nontemporal_load((const f32x2*)(oa + 256 + H * 16 + l * 4 + ph * 2));
        float m = fmaxf(lg[0], lg[1]);
        m = fmaxf(m, __shfl_xor(m, 1));
        m = fmaxf(m, __shfl_xor(m, 2));
        m = fmaxf(m, __shfl_xor(m, 4));
        float e0 = __expf(lg[0] - m), e1 = __expf(lg[1] - m);
        float s = e0 + e1;
        s += __shfl_xor(s, 1);
        s += __shfl_xor(s, 2);
        s += __shfl_xor(s, 4);
        const float inv = 1.f / s;
        const float aw2[2] = {e0 * inv, e1 * inv};

        f32x4 off4 = __builtin_nontemporal_load((const f32x4*)(oa + H * 32 + l * 8 + ph * 4));
        f32x2 rp = *(const f32x2*)(refpts + (size_t)(qbase + q) * 8 + l * 2);

        const int   SZ[4] = {128, 64, 32, 16};
        const int   ST[4] = {0, 16384, 20480, 21504};
        const int   W_ = SZ[l], START = ST[l];
        const float S = (float)W_;

        unsigned* dst = &s_iw[g * 68 + (l * 4 + ph * 2) * 4];
#pragma unroll
        for (int c = 0; c < 2; c++) {
            const float ox = off4[c * 2], oy = off4[c * 2 + 1];
            const float a = aw2[c];
            const float gx = fmaf(rp[0], S, ox) - 0.5f;
            const float gy = fmaf(rp[1], S, oy) - 0.5f;
            const float x0f = floorf(gx), y0f = floorf(gy);
            const float lx = gx - x0f, ly = gy - y0f;
            const int x0 = (int)x0f, y0 = (int)y0f;
            // x pair, clamped to [0, W-2]; shift weights to match clamp
            const int xs  = min(max(x0, 0), W_ - 2);
            const int sft = xs - x0;
            const float wx0 = (x0 >= 0 && x0 < W_) ? (1.f - lx) : 0.f;
            const float wx1 = (x0 + 1 >= 0 && x0 + 1 < W_) ? lx : 0.f;
            const float wxA = (sft == 0) ? wx0 : ((sft == 1) ? wx1 : 0.f);
            const float wxB = (sft == 0) ? wx1 : ((sft == -1) ? wx0 : 0.f);
            // y rows independent: clamp address, zero weight
            const int y1 = y0 + 1;
            const int y0c = min(max(y0, 0), W_ - 1);
            const int y1c = min(max(y1, 0), W_ - 1);
            const float wy0 = ((y0 >= 0) && (y0 < W_)) ? (1.f - ly) * a : 0.f;
            const float wy1 = ((y1 >= 0) && (y1 < W_)) ? ly * a : 0.f;
            u32x4 rec;
            rec[0] = (unsigned)((START + y0c * W_ + xs) * 64);
            rec[1] = (unsigned)((START + y1c * W_ + xs) * 64);
            rec[2] = pack2bf(wxA, wxB);
            rec[3] = pack2bf(wy0, wy1);
            *(u32x4*)(dst + c * 4) = rec;
        }
    }
    __syncthreads();

    // ---------------- phase 2 ----------------
    {
        const int d8 = tid & 3;
        const int xc = (tid >> 2) & 1;
        const int g  = tid >> 3;          // q*2 + h
        const int q  = g >> 1;
        const int h  = g & 1;
        const int H  = hp * 2 + h;
        const char* hb = (const char*)value_t + (size_t)H * HEAD_IMG_BYTES + xc * 64 + d8 * 16;
        const unsigned* iw = &s_iw[g * 68];

        float acc[8] = {0.f, 0.f, 0.f, 0.f, 0.f, 0.f, 0.f, 0.f};
#pragma unroll
        for (int p = 0; p < 16; p++) {
            const u32x4 t = *(const u32x4*)(iw + p * 4);
            const float wx = __uint_as_float(xc ? (t[2] & 0xffff0000u) : (t[2] << 16));
            const float w0 = __uint_as_float(t[3] << 16) * wx;
            const float w1 = __uint_as_float(t[3] & 0xffff0000u) * wx;
            const f16x8 v0 = *(const f16x8*)(hb + t[0]);
            const f16x8 v1 = *(const f16x8*)(hb + t[1]);
#pragma unroll
            for (int r = 0; r < 8; r++) {
                acc[r] = fmaf((float)v0[r], w0, acc[r]);   // v_fma_mix_f32
                acc[r] = fmaf((float)v1[r], w1, acc[r]);
            }
        }
#pragma unroll
        for (int j = 0; j < 8; j++) acc[j] += __shfl_xor(acc[j], 4);

        if (xc == 0) {
            s16x8 o = pack8(make_float4(acc[0], acc[1], acc[2], acc[3]),
                            make_float4(acc[4], acc[5], acc[6], acc[7]));
            *(s16x8*)(sampled + (size_t)(qbase + q) * 256 + H * 32 + d8 * 8) = o;
        }
    }
}

// ---------------------------------------------------------------------------
extern "C" void kernel_launch(void* const* d_in, const int* in_sizes, int n_in,
                              void* d_out, int out_size, void* d_ws, size_t ws_size,
                              hipStream_t stream) {
    const float* query  = (const float*)d_in[0];
    const float* refpts = (const float*)d_in[1];
    const float* input_flatten = (const float*)d_in[2];
    const float* W_off  = (const float*)d_in[5];
    const float* b_off  = (const float*)d_in[6];
    const float* W_attn = (const float*)d_in[7];
    const float* b_attn = (const float*)d_in[8];
    const float* W_val  = (const float*)d_in[9];
    const float* b_val  = (const float*)d_in[10];
    const float* W_out  = (const float*)d_in[11];
    const float* b_out  = (const float*)d_in[12];
    float* out = (float*)d_out;

    char* ws = (char*)d_ws;
    f16*            value_t = (f16*)ws;                                    // 8*Q*32 f16
    float*          offattn = (float*)(ws + 11141120);                     // Q*384 f32
    unsigned short* sampled = (unsigned short*)(ws + 44564480);            // Q*256 bf16
    unsigned short* w16     = (unsigned short*)(ws + 55705600);            // 229376 bf16
    float*          bias_cat= (float*)(ws + 56164352);                     // 384 f32
    unsigned short* w16_val  = w16 + 98304;
    unsigned short* w16_out  = w16 + 163840;

    cvt_weights<<<225, 256, 0, stream>>>(W_off, W_attn, W_val, W_out, b_off, b_attn, w16, bias_cat);

    // value_t[h][pix][32] = (input_flatten @ W_val^T + b_val), per-head transposed, f16
    gemm_mfma<false, true , true ><<<dim3(NBLK_M, 2), 256, 0, stream>>>(input_flatten, w16_val, b_val, value_t, 256);
    // [offsets | attn logits] = query @ [W_off;W_attn]^T + bias_cat (f32)
    gemm_mfma<false, false, false><<<dim3(NBLK_M, 3), 256, 0, stream>>>(query, w16, bias_cat, offattn, 384);
    // bilinear sampling + attention-weighted sum
    sample_kernel<<<dim3((Q_TOTAL / QB) * 4), 256, 0, stream>>>(value_t, offattn, refpts, sampled);
    // out = sampled @ W_out^T + b_out
    gemm_mfma<true,  false, false><<<dim3(NBLK_M, 2), 256, 0, stream>>>(sampled, w16_out, b_out, out, 256);
}

// Round 8
// 81.304 us; speedup vs baseline: 2.9982x; 1.0198x over previous
//
#include <hip/hip_runtime.h>
#include <math.h>

#define Q_TOTAL 21760
#define NBLK_M 340   // 21760 / 64
#define QB 16        // queries per sampling block
#define HEAD_IMG_BYTES 1392640   // 21760 * 32 * 2  (one head's transposed image, f16)

typedef _Float16     f16;
typedef short        s16x8 __attribute__((ext_vector_type(8)));
typedef f16          f16x8 __attribute__((ext_vector_type(8)));
typedef f16          f16x4 __attribute__((ext_vector_type(4)));
typedef f16          f16x2 __attribute__((ext_vector_type(2)));
typedef __bf16       bfv8  __attribute__((ext_vector_type(8)));
typedef float        f32x4 __attribute__((ext_vector_type(4)));
typedef float        f32x2 __attribute__((ext_vector_type(2)));
typedef unsigned int u32x4 __attribute__((ext_vector_type(4)));

// pack 8 floats -> 8 bf16 (RNE; compiler emits v_cvt_pk_bf16_f32)
__device__ __forceinline__ s16x8 pack8(float4 a, float4 b) {
    bfv8 t;
    t[0] = (__bf16)a.x; t[1] = (__bf16)a.y; t[2] = (__bf16)a.z; t[3] = (__bf16)a.w;
    t[4] = (__bf16)b.x; t[5] = (__bf16)b.y; t[6] = (__bf16)b.z; t[7] = (__bf16)b.w;
    return __builtin_bit_cast(s16x8, t);
}

// ---------------------------------------------------------------------------
// Convert the 4 weight matrices to bf16 + build concat bias [b_off|b_attn].
// dst layout: [W_off 65536 | W_attn 32768 | W_val 65536 | W_out 65536]
// ---------------------------------------------------------------------------
__global__ __launch_bounds__(256) void cvt_weights(
    const float* __restrict__ Woff, const float* __restrict__ Wattn,
    const float* __restrict__ Wval, const float* __restrict__ Wout,
    const float* __restrict__ boff, const float* __restrict__ battn,
    unsigned short* __restrict__ dst, float* __restrict__ bias_cat)
{
    if (blockIdx.x == 224) {
        const int t = threadIdx.x;
        bias_cat[t] = boff[t];
        if (t < 128) bias_cat[256 + t] = battn[t];
        return;
    }
    const int e = blockIdx.x * 1024 + threadIdx.x * 4;
    const float* src; int base;
    if (e < 65536)       { src = Woff;  base = 0; }
    else if (e < 98304)  { src = Wattn; base = 65536; }
    else if (e < 163840) { src = Wval;  base = 98304; }
    else                 { src = Wout;  base = 163840; }
    float4 v = *(const float4*)(src + (e - base));
    ushort4 o;
    o.x = __builtin_bit_cast(unsigned short, (__bf16)v.x);
    o.y = __builtin_bit_cast(unsigned short, (__bf16)v.y);
    o.z = __builtin_bit_cast(unsigned short, (__bf16)v.z);
    o.w = __builtin_bit_cast(unsigned short, (__bf16)v.w);
    *(ushort4*)(dst + e) = o;
}

// ---------------------------------------------------------------------------
// MFMA bf16 GEMM: C slab = A[M][256] @ W[colBase..colBase+127][256]^T + bias
// BM=64, BN=128 slab, BK=32, 256 threads = 4 waves (2x2).
// CMODE: 0 = f32 flat, 1 = f16 flat, 2 = f16 per-head transposed (value_t).
// ---------------------------------------------------------------------------
template<bool A_BF16, int CMODE>
__global__ __launch_bounds__(256) void gemm_mfma(
    const void* __restrict__ Avoid,
    const unsigned short* __restrict__ W16,
    const float* __restrict__ bias,
    void* __restrict__ Cvoid,
    int ldc)
{
    constexpr int K = 256, BM = 64, BN = 128;
    constexpr int NB2 = BN / 2;          // 64 cols per wave-col
    constexpr int NF = NB2 / 16;         // 4 frags
    __shared__ unsigned short As[BM * 32];
    __shared__ unsigned short Bs[BN * 32];

    const int tid  = threadIdx.x;
    const int lane = tid & 63;
    const int wv   = tid >> 6;
    const int wr   = wv >> 1, wc = wv & 1;
    const int rowBase = blockIdx.x * BM;
    const int colBase = blockIdx.y * BN;

    const int sr    = tid >> 2;          // staging row 0..63
    const int skq   = (tid & 3) * 8;     // 8 elems per thread along K
    const int sslot = (tid & 3) * 16;    // byte slot within 64B row

    f32x4 acc[2][NF];
#pragma unroll
    for (int i = 0; i < 2; i++)
#pragma unroll
        for (int j = 0; j < NF; j++) acc[i][j] = (f32x4){0.f, 0.f, 0.f, 0.f};

    const size_t arow = (size_t)(rowBase + sr) * K;

    for (int kt = 0; kt < K; kt += 32) {
        s16x8 aval;
        if constexpr (A_BF16) {
            const unsigned short* A16 = (const unsigned short*)Avoid;
            aval = *(const s16x8*)(A16 + arow + kt + skq);
        } else {
            const float* A32 = (const float*)Avoid;
            const float* p = A32 + arow + kt + skq;
            aval = pack8(*(const float4*)p, *(const float4*)(p + 4));
        }
        s16x8 bval[2];
#pragma unroll
        for (int c = 0; c < 2; c++) {
            const unsigned short* p = W16 + (size_t)(colBase + c * 64 + sr) * K + kt + skq;
            bval[c] = *(const s16x8*)p;
        }
        __syncthreads();
        *(s16x8*)(As + (((sr * 64 + sslot) ^ ((sr & 7) << 4)) >> 1)) = aval;
#pragma unroll
        for (int c = 0; c < 2; c++) {
            const int row = c * 64 + sr;
            *(s16x8*)(Bs + (((row * 64 + sslot) ^ ((row & 7) << 4)) >> 1)) = bval[c];
        }
        __syncthreads();
        s16x8 af[2];
#pragma unroll
        for (int mi = 0; mi < 2; mi++) {
            const int row = wr * 32 + mi * 16 + (lane & 15);
            af[mi] = *(const s16x8*)(As + (((row * 64 + (lane >> 4) * 16) ^ ((row & 7) << 4)) >> 1));
        }
#pragma unroll
        for (int ni = 0; ni < NF; ni++) {
            const int row = wc * NB2 + ni * 16 + (lane & 15);
            s16x8 bfrag = *(const s16x8*)(Bs + (((row * 64 + (lane >> 4) * 16) ^ ((row & 7) << 4)) >> 1));
#pragma unroll
            for (int mi = 0; mi < 2; mi++)
                acc[mi][ni] = __builtin_amdgcn_mfma_f32_16x16x32_bf16(af[mi], bfrag, acc[mi][ni], 0, 0, 0);
        }
    }

#pragma unroll
    for (int ni = 0; ni < NF; ni++) {
        const int col = colBase + wc * NB2 + ni * 16 + (lane & 15);
        const float bv = bias[col];
#pragma unroll
        for (int mi = 0; mi < 2; mi++) {
            const int r0 = rowBase + wr * 32 + mi * 16 + (lane >> 4) * 4;
#pragma unroll
            for (int j = 0; j < 4; j++) {
                const float v = acc[mi][ni][j] + bv;
                if constexpr (CMODE == 2) {
                    // value_t[h][pix][32] f16, h = col>>5
                    ((f16*)Cvoid)[((size_t)(col >> 5) * Q_TOTAL + (r0 + j)) * 32 + (col & 31)] = (f16)v;
                } else if constexpr (CMODE == 1) {
                    ((f16*)Cvoid)[(size_t)(r0 + j) * ldc + col] = (f16)v;
                } else {
                    ((float*)Cvoid)[(size_t)(r0 + j) * ldc + col] = v;
                }
            }
        }
    }
}

// ---------------------------------------------------------------------------
// Sampling: block = 16 queries x 2 heads (256 threads).
// bid = qtile*4 + headpair -> bid%8 in {hp, hp+4}: each XCD touches only
// its 2-head value slice (2.78 MB < 4 MB L2) in the transposed f16 layout.
// Phase 1 (tid = q*16 + h*8 + l*2 + ph): softmax over 8-lane group; per point
// and per x-corner writes a pre-folded rec {o0+xc*64, o1+xc*64,
// f32(a*wy0*wx_xc), f32(a*wy1*wx_xc)} as u32x4 into LDS.
// Phase 2 (tid = q*16 + h*8 + xc*4 + d8): per point 1 ds_read_b128 (weights
// pre-folded, no unpack) + 2 f16x8 row loads + 16 fma_mix; xor(4) reduce
// combines corners.
// Group stride 132 words -> (g,xc) groups at banks 4(g+xc): 2-way max (free).
// ---------------------------------------------------------------------------
__global__ __launch_bounds__(256) void sample_kernel(
    const f16* __restrict__ value_t,             // [8][Q][32] f16
    const f16* __restrict__ offattn,             // [Q][384] f16
    const float* __restrict__ refpts,            // [Q][4][2] f32
    unsigned short* __restrict__ sampled)        // [Q][256] bf16
{
    __shared__ __attribute__((aligned(16))) unsigned s_iw[32 * 132];

    const int tid   = threadIdx.x;
    const int qt    = blockIdx.x >> 2;
    const int hp    = blockIdx.x & 3;
    const int qbase = qt * QB;

    // ---------------- phase 1 ----------------
    {
        const int q  = tid >> 4;
        const int h  = (tid >> 3) & 1;
        const int l  = (tid >> 1) & 3;
        const int ph = tid & 1;
        const int H  = hp * 2 + h;
        const int g  = tid >> 3;         // q*2 + h
        const f16* oa = offattn + (size_t)(qbase + q) * 384;

        f16x2 lgh = *(const f16x2*)(oa + 256 + H * 16 + l * 4 + ph * 2);
        const float lg0 = (float)lgh[0], lg1 = (float)lgh[1];
        float m = fmaxf(lg0, lg1);
        m = fmaxf(m, __shfl_xor(m, 1));
        m = fmaxf(m, __shfl_xor(m, 2));
        m = fmaxf(m, __shfl_xor(m, 4));
        float e0 = __expf(lg0 - m), e1 = __expf(lg1 - m);
        float s = e0 + e1;
        s += __shfl_xor(s, 1);
        s += __shfl_xor(s, 2);
        s += __shfl_xor(s, 4);
        const float inv = 1.f / s;
        const float aw2[2] = {e0 * inv, e1 * inv};

        f16x4 offh = *(const f16x4*)(oa + H * 32 + l * 8 + ph * 4);
        f32x2 rp = *(const f32x2*)(refpts + (size_t)(qbase + q) * 8 + l * 2);

        const int   SZ[4] = {128, 64, 32, 16};
        const int   ST[4] = {0, 16384, 20480, 21504};
        const int   W_ = SZ[l], START = ST[l];
        const float S = (float)W_;

        unsigned* dst = &s_iw[g * 132 + (l * 4 + ph * 2) * 8];
#pragma unroll
        for (int c = 0; c < 2; c++) {
            const float ox = (float)offh[c * 2], oy = (float)offh[c * 2 + 1];
            const float a = aw2[c];
            const float gx = fmaf(rp[0], S, ox) - 0.5f;
            const float gy = fmaf(rp[1], S, oy) - 0.5f;
            const float x0f = floorf(gx), y0f = floorf(gy);
            const float lx = gx - x0f, ly = gy - y0f;
            const int x0 = (int)x0f, y0 = (int)y0f;
            // x pair, clamped to [0, W-2]; shift weights to match clamp
            const int xs  = min(max(x0, 0), W_ - 2);
            const int sft = xs - x0;
            const float wx0 = (x0 >= 0 && x0 < W_) ? (1.f - lx) : 0.f;
            const float wx1 = (x0 + 1 >= 0 && x0 + 1 < W_) ? lx : 0.f;
            const float wxA = (sft == 0) ? wx0 : ((sft == 1) ? wx1 : 0.f);
            const float wxB = (sft == 0) ? wx1 : ((sft == -1) ? wx0 : 0.f);
            // y rows independent: clamp address, zero weight
            const int y1 = y0 + 1;
            const int y0c = min(max(y0, 0), W_ - 1);
            const int y1c = min(max(y1, 0), W_ - 1);
            const float wy0a = (((y0 >= 0) && (y0 < W_)) ? (1.f - ly) : 0.f) * a;
            const float wy1a = (((y1 >= 0) && (y1 < W_)) ? ly : 0.f) * a;
            const unsigned o0 = (unsigned)((START + y0c * W_ + xs) * 64);
            const unsigned o1 = (unsigned)((START + y1c * W_ + xs) * 64);
            u32x4 r0, r1;
            r0[0] = o0;      r0[1] = o1;
            r0[2] = __float_as_uint(wy0a * wxA);
            r0[3] = __float_as_uint(wy1a * wxA);
            r1[0] = o0 + 64; r1[1] = o1 + 64;
            r1[2] = __float_as_uint(wy0a * wxB);
            r1[3] = __float_as_uint(wy1a * wxB);
            *(u32x4*)(dst + c * 8)     = r0;
            *(u32x4*)(dst + c * 8 + 4) = r1;
        }
    }
    __syncthreads();

    // ---------------- phase 2 ----------------
    {
        const int d8 = tid & 3;
        const int xc = (tid >> 2) & 1;
        const int g  = tid >> 3;          // q*2 + h
        const int q  = g >> 1;
        const int h  = g & 1;
        const int H  = hp * 2 + h;
        const char* hb = (const char*)value_t + (size_t)H * HEAD_IMG_BYTES + d8 * 16;
        const unsigned* iw = &s_iw[g * 132 + xc * 4];

        float acc[8] = {0.f, 0.f, 0.f, 0.f, 0.f, 0.f, 0.f, 0.f};
#pragma unroll
        for (int p = 0; p < 16; p++) {
            const u32x4 t = *(const u32x4*)(iw + p * 8);
            const float w0 = __uint_as_float(t[2]);
            const float w1 = __uint_as_float(t[3]);
            const f16x8 v0 = *(const f16x8*)(hb + t[0]);
            const f16x8 v1 = *(const f16x8*)(hb + t[1]);
#pragma unroll
            for (int r = 0; r < 8; r++) {
                acc[r] = fmaf((float)v0[r], w0, acc[r]);   // v_fma_mix_f32
                acc[r] = fmaf((float)v1[r], w1, acc[r]);
            }
        }
#pragma unroll
        for (int j = 0; j < 8; j++) acc[j] += __shfl_xor(acc[j], 4);

        if (xc == 0) {
            s16x8 o = pack8(make_float4(acc[0], acc[1], acc[2], acc[3]),
                            make_float4(acc[4], acc[5], acc[6], acc[7]));
            *(s16x8*)(sampled + (size_t)(qbase + q) * 256 + H * 32 + d8 * 8) = o;
        }
    }
}

// ---------------------------------------------------------------------------
extern "C" void kernel_launch(void* const* d_in, const int* in_sizes, int n_in,
                              void* d_out, int out_size, void* d_ws, size_t ws_size,
                              hipStream_t stream) {
    const float* query  = (const float*)d_in[0];
    const float* refpts = (const float*)d_in[1];
    const float* input_flatten = (const float*)d_in[2];
    const float* W_off  = (const float*)d_in[5];
    const float* b_off  = (const float*)d_in[6];
    const float* W_attn = (const float*)d_in[7];
    const float* b_attn = (const float*)d_in[8];
    const float* W_val  = (const float*)d_in[9];
    const float* b_val  = (const float*)d_in[10];
    const float* W_out  = (const float*)d_in[11];
    const float* b_out  = (const float*)d_in[12];
    float* out = (float*)d_out;

    char* ws = (char*)d_ws;
    f16*            value_t = (f16*)ws;                                    // 8*Q*32 f16   = 11141120 B
    f16*            offattn = (f16*)(ws + 11141120);                       // Q*384 f16    = 16711680 B
    unsigned short* sampled = (unsigned short*)(ws + 27852800);            // Q*256 bf16   = 11141120 B
    unsigned short* w16     = (unsigned short*)(ws + 38993920);            // 229376 bf16
    float*          bias_cat= (float*)(ws + 39452672);                     // 384 f32
    unsigned short* w16_val  = w16 + 98304;
    unsigned short* w16_out  = w16 + 163840;

    cvt_weights<<<225, 256, 0, stream>>>(W_off, W_attn, W_val, W_out, b_off, b_attn, w16, bias_cat);

    // value_t[h][pix][32] = (input_flatten @ W_val^T + b_val), per-head transposed, f16
    gemm_mfma<false, 2><<<dim3(NBLK_M, 2), 256, 0, stream>>>(input_flatten, w16_val, b_val, value_t, 256);
    // [offsets | attn logits] = query @ [W_off;W_attn]^T + bias_cat (f16 out)
    gemm_mfma<false, 1><<<dim3(NBLK_M, 3), 256, 0, stream>>>(query, w16, bias_cat, offattn, 384);
    // bilinear sampling + attention-weighted sum
    sample_kernel<<<dim3((Q_TOTAL / QB) * 4), 256, 0, stream>>>(value_t, offattn, refpts, sampled);
    // out = sampled @ W_out^T + b_out (f32 out)
    gemm_mfma<true, 0><<<dim3(NBLK_M, 2), 256, 0, stream>>>(sampled, w16_out, b_out, out, 256);
}